// Round 10
// baseline (15309.468 us; speedup 1.0000x reference)
//
#include <hip/hip_runtime.h>
#include <hip/hip_bf16.h>

// FP32-intermediate pipeline (recurrence is chaotic; bf16 rounding decorrelates).
// R10: GEMM is LDS-BW-bound at 1 B/FLOP (three configs pinned ~285us). Fix:
//      128x128 tile + 8x8 micro (0.5 B/FLOP) + split-k=4 grid. Also bf16 WbT
//      for the gate/cand weight merge (bit-exact in bf16-world, halves L2).

#define B_    16
#define T_    12
#define N_    2048
#define HID_  64
#define ED_   10
#define HOR_  12
#define BH    (B_*HID_)    // 1024
#define BT    (B_*T_)      // 192
#define KS    4            // split-k slices
#define MSL   (N_/KS)      // 512 m's per slice

typedef __hip_bfloat16 bf16;
__device__ __forceinline__ float b2f(bf16 x){ return __bfloat162float(x); }
__device__ __forceinline__ bf16  f2b(float x){ return __float2bfloat16(x); }
__device__ __forceinline__ float bits2f(unsigned u) {
  union { float f; unsigned i; } c; c.i = u << 16; return c.f;
}

__device__ __forceinline__ float ldin(const void* p, size_t i, int isbf) {
  return isbf ? b2f(((const bf16*)p)[i]) : ((const float*)p)[i];
}
__device__ __forceinline__ void fma4(float4& a, float s, const float4& b) {
  a.x += s*b.x; a.y += s*b.y; a.z += s*b.z; a.w += s*b.w;
}

// ---------------------------------------------------------------------------
// dtype detector on E (bits 14:7 of 32-bit words: bf16 exponent vs mantissa)
// ---------------------------------------------------------------------------
__global__ void k_detect(const void* __restrict__ E, int* __restrict__ flag) {
  __shared__ int cnt;
  if (threadIdx.x == 0) cnt = 0;
  __syncthreads();
  const unsigned* w = (const unsigned*)E;
  int c = 0;
  for (int i = threadIdx.x; i < 4096; i += 256) {
    const unsigned e = (w[i] >> 7) & 0xFFu;
    if (e >= 0x6Eu && e <= 0x86u) ++c;
  }
  atomicAdd(&cnt, c);
  __syncthreads();
  if (threadIdx.x == 0) flag[0] = (cnt > 2048) ? 1 : 0;
}

// --- input casts to fp32 internal buffers ---
__global__ void k_castE(const void* __restrict__ E, float* __restrict__ Ein,
                        const int* __restrict__ flag) {
  const int i = blockIdx.x*256 + threadIdx.x;
  if (i < N_*ED_) Ein[i] = ldin(E, i, flag[0]);
}
__global__ void k_castsrc(const void* __restrict__ src, float* __restrict__ srcf,
                          const int* __restrict__ flag) {
  const int i = blockIdx.x*256 + threadIdx.x;
  if (i < B_*T_*N_) srcf[i] = ldin(src, i, flag[0]);
}
__global__ void k_castc(const void* __restrict__ cw, const void* __restrict__ cb,
                        float* __restrict__ cwf, float* __restrict__ cbf,
                        const int* __restrict__ flag) {
  const int i = blockIdx.x*256 + threadIdx.x;
  const int f = flag[0];
  if (i < HOR_*HID_) cwf[i] = ldin(cw, i, f);
  if (i < HOR_)      cbf[i] = ldin(cb, i, f);
}

// ---------------------------------------------------------------------------
// S = softmax(relu(Ein @ Ein^T), axis=1) -> fp32 row-major
// ---------------------------------------------------------------------------
__global__ __launch_bounds__(256) void k_softmax_S(const float* __restrict__ Ein,
                                                   float* __restrict__ S) {
  const int n = blockIdx.x, tid = threadIdx.x;
  __shared__ float er[ED_];
  __shared__ float red[4];
  if (tid < ED_) er[tid] = Ein[n*ED_ + tid];
  __syncthreads();
  float e[ED_];
#pragma unroll
  for (int d = 0; d < ED_; ++d) e[d] = er[d];
  float v[8];
  float mx = 0.f;
#pragma unroll
  for (int j = 0; j < 8; ++j) {
    const int m = tid + j*256;
    float dot = 0.f;
#pragma unroll
    for (int d = 0; d < ED_; ++d) dot += e[d]*Ein[m*ED_ + d];
    v[j] = fmaxf(dot, 0.f);
    mx = fmaxf(mx, v[j]);
  }
  for (int o = 32; o; o >>= 1) mx = fmaxf(mx, __shfl_xor(mx, o, 64));
  if ((tid & 63) == 0) red[tid >> 6] = mx;
  __syncthreads();
  mx = fmaxf(fmaxf(red[0], red[1]), fmaxf(red[2], red[3]));
  __syncthreads();
  float sum = 0.f;
#pragma unroll
  for (int j = 0; j < 8; ++j) { v[j] = __expf(v[j] - mx); sum += v[j]; }
  for (int o = 32; o; o >>= 1) sum += __shfl_xor(sum, o, 64);
  if ((tid & 63) == 0) red[tid >> 6] = sum;
  __syncthreads();
  sum = red[0] + red[1] + red[2] + red[3];
  const float inv = 1.f / sum;
#pragma unroll
  for (int j = 0; j < 8; ++j)
    S[(size_t)n*N_ + tid + j*256] = v[j]*inv;
}

// ---------------------------------------------------------------------------
// Basis weights, transposed + K-remapped: fp32 AND bf16 copies.
// LAYER0 (KIin=65,KIP=160): kp<64 ->(cheb0,kp+1); kp==64 ->(cheb0,0);
//   80<=kp<144 ->(cheb1,kp-79); kp==144 ->(cheb1,0); else 0.
// LAYER1 (KIin=128,KIP=256): cheb=kp>>7, i=kp&127.
// ---------------------------------------------------------------------------
template<int LAYER>
__global__ __launch_bounds__(256) void k_prepT(const void* __restrict__ Wb,
                                               float* __restrict__ WbF,
                                               bf16* __restrict__ WbH,
                                               int KIin, int KIP, int O,
                                               const int* __restrict__ flag) {
  const int idx = blockIdx.x*256 + threadIdx.x;
  if (idx >= ED_*O*KIP) return;
  const int d = idx / (O*KIP), rem = idx - d*O*KIP;
  const int o = rem / KIP, kp = rem - o*KIP;
  int cheb, i; bool valid;
  if (LAYER == 0) {
    cheb = (kp >= 80) ? 1 : 0;
    const int local = kp - cheb*80;
    if (local < 64)       { i = local + 1; valid = true; }
    else if (local == 64) { i = 0;         valid = true; }
    else                  { i = 0;         valid = false; }
  } else {
    cheb = kp >> 7; i = kp & 127; valid = true;
  }
  float v = 0.f;
  if (valid) v = ldin(Wb, (size_t)((d*2 + cheb)*KIin + i)*O + o, flag[0]);
  WbF[(size_t)(d*O + o)*KIP + kp] = v;
  WbH[(size_t)(d*O + o)*KIP + kp] = f2b(v);   // exact in bf16-world
}

// bias vectors: outv[n][o] = sum_d Ein[n,d]*bb[d][o]
__global__ __launch_bounds__(128) void k_matb(const float* __restrict__ Ein,
                                              const void* __restrict__ bb,
                                              float* __restrict__ outv, int O,
                                              const int* __restrict__ flag) {
  const int n = blockIdx.x, tid = threadIdx.x;
  if (tid >= O) return;
  const int f = flag[0];
  float acc = 0.f;
#pragma unroll
  for (int d = 0; d < ED_; ++d) acc += Ein[n*ED_ + d]*ldin(bb, d*O + tid, f);
  outv[n*O + tid] = acc;
}

// ---------------------------------------------------------------------------
// Small 64-tile GEMM for Sx0 only (XT form: X[c*ldx+m]); cols = BT = 192
// ---------------------------------------------------------------------------
__global__ __launch_bounds__(256) void k_gemm64T(const float* __restrict__ S,
                                                 const float* __restrict__ X,
                                                 float* __restrict__ C,
                                                 int ldx, int ldc) {
  const int bm = blockIdx.x * 64;
  const int bc = blockIdx.y * 64;
  __shared__ float St[64][68];
  __shared__ float Xt[64][68];
  const int tid = threadIdx.x;
  const int r0 = (tid >> 4) * 4;
  const int c0 = (tid & 15) * 4;
  float acc[4][4];
#pragma unroll
  for (int i = 0; i < 4; ++i)
#pragma unroll
    for (int j = 0; j < 4; ++j) acc[i][j] = 0.f;
  for (int mk = 0; mk < N_; mk += 64) {
    {
      const int r = tid >> 2, ks = (tid & 3) * 16;
      const float* sp = S + (size_t)(bm + r)*N_ + mk + ks;
#pragma unroll
      for (int u = 0; u < 16; ++u) St[ks + u][r] = sp[u];
      const float* xp = X + (size_t)(bc + r)*ldx + mk + ks;
#pragma unroll
      for (int u = 0; u < 16; ++u) Xt[ks + u][r] = xp[u];
    }
    __syncthreads();
#pragma unroll 4
    for (int kk = 0; kk < 64; ++kk) {
      const float a0 = St[kk][r0], a1 = St[kk][r0+1],
                  a2 = St[kk][r0+2], a3 = St[kk][r0+3];
      const float b0 = Xt[kk][c0], b1 = Xt[kk][c0+1],
                  b2 = Xt[kk][c0+2], b3 = Xt[kk][c0+3];
      acc[0][0] += a0*b0; acc[0][1] += a0*b1; acc[0][2] += a0*b2; acc[0][3] += a0*b3;
      acc[1][0] += a1*b0; acc[1][1] += a1*b1; acc[1][2] += a1*b2; acc[1][3] += a1*b3;
      acc[2][0] += a2*b0; acc[2][1] += a2*b1; acc[2][2] += a2*b2; acc[2][3] += a2*b3;
      acc[3][0] += a3*b0; acc[3][1] += a3*b1; acc[3][2] += a3*b2; acc[3][3] += a3*b3;
    }
    __syncthreads();
  }
#pragma unroll
  for (int i = 0; i < 4; ++i)
#pragma unroll
    for (int j = 0; j < 4; ++j)
      C[(size_t)(bm + r0 + i)*ldc + bc + c0 + j] = acc[i][j];
}

// ---------------------------------------------------------------------------
// Main split-k 128x128-tile fp32 GEMM, 8x8 micro-tile (2x2 blocks of 4x4 at
// +-64): C(n,c) += sum_{m in slice z} S[n,m]*X[m*ldx+c]. 0.5 B/FLOP LDS.
// Output must be PRE-ZEROED (atomicAdd epilogue). Grid: (16, cols/128, KS).
// Dual output: blockIdx.y*128 >= split -> X2/C2 (col rebased).
// ---------------------------------------------------------------------------
__global__ __launch_bounds__(256) void k_gemm8(const float* __restrict__ S,
                                               const float* __restrict__ X1,
                                               float* __restrict__ C1,
                                               int ldx1, int ldc1,
                                               const float* __restrict__ X2,
                                               float* __restrict__ C2,
                                               int ldx2, int ldc2,
                                               int split) {
  const int bm = blockIdx.x * 128;
  int bc = blockIdx.y * 128;
  const float* X = X1; float* C = C1; int ldx = ldx1, ldc = ldc1;
  if (bc >= split) { X = X2; C = C2; ldx = ldx2; ldc = ldc2; bc -= split; }
  const int mk0 = blockIdx.z * MSL;

  __shared__ float Ss[16][132];   // Ss[kk][r] = S[bm+r][mk+kk]
  __shared__ float Xs[16][136];   // Xs[kk][c] = X[mk+kk][bc+c]
  const int tid = threadIdx.x;
  const int r0 = (tid >> 4) * 4;  // rows r0..+3 and r0+64..+67
  const int c0 = (tid & 15) * 4;  // cols c0..+3 and c0+64..+67

  float acc[2][2][4][4];
#pragma unroll
  for (int u = 0; u < 2; ++u)
#pragma unroll
    for (int v = 0; v < 2; ++v)
#pragma unroll
      for (int i = 0; i < 4; ++i)
#pragma unroll
        for (int j = 0; j < 4; ++j) acc[u][v][i][j] = 0.f;

  for (int mk = mk0; mk < mk0 + MSL; mk += 16) {
    // stage S tile: 128 rows x 16 k (512 float4, transposed scatter)
#pragma unroll
    for (int u = 0; u < 2; ++u) {
      const int idx = tid + u*256;
      const int r = idx >> 2, kq = (idx & 3) * 4;
      const float4 v4 = *(const float4*)(S + (size_t)(bm + r)*N_ + mk + kq);
      Ss[kq + 0][r] = v4.x; Ss[kq + 1][r] = v4.y;
      Ss[kq + 2][r] = v4.z; Ss[kq + 3][r] = v4.w;
    }
    // stage X tile: 16 k x 128 c (512 float4, natural)
#pragma unroll
    for (int u = 0; u < 2; ++u) {
      const int idx = tid + u*256;
      const int kk = idx >> 5, cq = (idx & 31) * 4;
      *(float4*)&Xs[kk][cq] = *(const float4*)(X + (size_t)(mk + kk)*ldx + bc + cq);
    }
    __syncthreads();
#pragma unroll
    for (int kk = 0; kk < 16; ++kk) {
      const float4 aA = *(const float4*)&Ss[kk][r0];
      const float4 aB = *(const float4*)&Ss[kk][r0 + 64];
      const float4 bA = *(const float4*)&Xs[kk][c0];
      const float4 bB = *(const float4*)&Xs[kk][c0 + 64];
      const float ar[2][4]  = {{aA.x,aA.y,aA.z,aA.w},{aB.x,aB.y,aB.z,aB.w}};
      const float bc4[2][4] = {{bA.x,bA.y,bA.z,bA.w},{bB.x,bB.y,bB.z,bB.w}};
#pragma unroll
      for (int u = 0; u < 2; ++u)
#pragma unroll
        for (int v = 0; v < 2; ++v)
#pragma unroll
          for (int i = 0; i < 4; ++i)
#pragma unroll
            for (int j = 0; j < 4; ++j)
              acc[u][v][i][j] += ar[u][i]*bc4[v][j];
    }
    __syncthreads();
  }
#pragma unroll
  for (int u = 0; u < 2; ++u)
#pragma unroll
    for (int i = 0; i < 4; ++i)
#pragma unroll
      for (int v = 0; v < 2; ++v)
#pragma unroll
        for (int j = 0; j < 4; ++j)
          atomicAdd(C + (size_t)(bm + r0 + i + 64*u)*ldc + bc + c0 + 64*v + j,
                    acc[u][v][i][j]);
}

// ---------------------------------------------------------------------------
// xg builder (float4): xg[b][k], padded row stride KIPP.
// LAYER0 (KIP=160): k<64:h(p0); k==64:x(p1,(b*T+t)*N+n); [80,144):Sh(p2);
//   k==144:Sx(p3,n*BT+b*T+t); else 0.
// LAYER1 (KIP=256): [0,64)p0 |[64,128)p1 |[128,192)p2 |[192,256)p3, n-major.
// ---------------------------------------------------------------------------
template<int LAYER, int KIP, int KIPP>
__device__ __forceinline__ void build4(float (*xg)[KIPP],
                                       const float* p0, const float* p1,
                                       const float* p2, const float* p3,
                                       int n, int t, int tid) {
  constexpr int NQ = KIP/4;
  for (int idx = tid; idx < B_*NQ; idx += 256) {
    const int b = idx / NQ, k = (idx - b*NQ) * 4;
    float4 v = make_float4(0.f, 0.f, 0.f, 0.f);
    if (LAYER == 1) {
      const float* rg = (k < 64) ? p0 : (k < 128) ? p1 : (k < 192) ? p2 : p3;
      v = *(const float4*)(rg + (size_t)n*BH + b*64 + (k & 63));
    } else {
      if (k < 64)        v = *(const float4*)(p0 + (size_t)n*BH + b*64 + k);
      else if (k == 64)  v.x = p1[(size_t)(b*T_ + t)*N_ + n];
      else if (k >= 80 && k < 144)
                         v = *(const float4*)(p2 + (size_t)n*BH + b*64 + (k - 80));
      else if (k == 144) v.x = p3[(size_t)n*BT + b*T_ + t];
    }
    *(float4*)&xg[b][k] = v;
  }
}

// merge helper: wm-row accumulate, dtype-switched (uniform branch on isbf)
template<int O, int KIP>
__device__ __forceinline__ float4 merge_w(const float* WbF, const bf16* WbH,
                                          const float* el, int o, int kq,
                                          int isbf) {
  float4 a4 = make_float4(0.f, 0.f, 0.f, 0.f);
  if (isbf) {
    const bf16* wp = WbH + (size_t)o*KIP + kq;
#pragma unroll
    for (int d = 0; d < ED_; ++d) {
      const uint2 w2 = *(const uint2*)(wp + (size_t)d*O*KIP);
      a4.x += el[d]*bits2f(w2.x & 0xFFFFu);
      a4.y += el[d]*bits2f(w2.x >> 16);
      a4.z += el[d]*bits2f(w2.y & 0xFFFFu);
      a4.w += el[d]*bits2f(w2.y >> 16);
    }
  } else {
    const float* wp = WbF + (size_t)o*KIP + kq;
#pragma unroll
    for (int d = 0; d < ED_; ++d)
      fma4(a4, el[d], *(const float4*)(wp + (size_t)d*O*KIP));
  }
  return a4;
}

// ---------------------------------------------------------------------------
// Gate: y[b,o] = sigmoid(sum_d E[n,d]*(xg[b,:]@Wb[d][:,o]) + bgv[n,o]), O=128.
// ---------------------------------------------------------------------------
template<int LAYER, int KIP>
__global__ __launch_bounds__(256) void k_gateW(const float* __restrict__ WbF,
                                               const bf16* __restrict__ WbH,
                                               const float* __restrict__ bgv,
                                               const float* __restrict__ p0,
                                               const float* __restrict__ p1,
                                               const float* __restrict__ p2,
                                               const float* __restrict__ p3,
                                               const float* __restrict__ Ein,
                                               const float* __restrict__ hstate,
                                               float* __restrict__ zh,
                                               float* __restrict__ r_buf,
                                               const int* __restrict__ flag,
                                               int t) {
  constexpr int KIPP = KIP + 4;
  constexpr int O = 128;
  const int n = blockIdx.x, tid = threadIdx.x;
  __shared__ float xg[B_][KIPP];
  __shared__ float wm[O][36];
  __shared__ float es[ED_];
  if (tid < ED_) es[tid] = Ein[n*ED_ + tid];
  build4<LAYER, KIP, KIPP>(xg, p0, p1, p2, p3, n, t, tid);
  __syncthreads();
  const int isbf = flag[0];
  float el[ED_];
#pragma unroll
  for (int d = 0; d < ED_; ++d) el[d] = es[d];

  const int b = tid >> 4, q = tid & 15;
  float acc[8];
#pragma unroll
  for (int j = 0; j < 8; ++j) acc[j] = 0.f;

  for (int k0 = 0; k0 < KIP; k0 += 32) {
#pragma unroll
    for (int i = 0; i < O*8/256; ++i) {
      const int idx = tid + i*256;
      const int o = idx >> 3, kq = (idx & 7) * 4;
      const float4 a4 = merge_w<O, KIP>(WbF, WbH, el, o, k0 + kq, isbf);
      *(float4*)&wm[o][kq] = a4;
    }
    __syncthreads();
#pragma unroll
    for (int kq = 0; kq < 8; ++kq) {
      const float4 xv = *(const float4*)&xg[b][k0 + kq*4];
#pragma unroll
      for (int j = 0; j < 8; ++j) {
        const float4 wv = *(const float4*)&wm[q + 16*j][kq*4];
        acc[j] += xv.x*wv.x + xv.y*wv.y + xv.z*wv.z + xv.w*wv.w;
      }
    }
    __syncthreads();
  }
#pragma unroll
  for (int j = 0; j < 8; ++j) {
    const int o = q + 16*j;
    float s = acc[j] + bgv[n*128 + o];
    s = 1.f/(1.f + __expf(-s));
    if (o < HID_)
      zh[(size_t)n*BH + b*64 + o] = s*hstate[(size_t)n*BH + b*64 + o];
    else
      r_buf[(size_t)n*BH + b*64 + (o - HID_)] = s;
  }
}

// ---------------------------------------------------------------------------
// Candidate: hc = tanh(...); h = r*h + (1-r)*hc in place. O=64.
// ---------------------------------------------------------------------------
template<int LAYER, int KIP>
__global__ __launch_bounds__(256) void k_candW(const float* __restrict__ WbF,
                                               const bf16* __restrict__ WbH,
                                               const float* __restrict__ buv,
                                               const float* __restrict__ p0,
                                               const float* __restrict__ p1,
                                               const float* __restrict__ p2,
                                               const float* __restrict__ p3,
                                               const float* __restrict__ Ein,
                                               const float* __restrict__ r_buf,
                                               float* __restrict__ hstate,
                                               const int* __restrict__ flag,
                                               int t) {
  constexpr int KIPP = KIP + 4;
  constexpr int O = 64;
  const int n = blockIdx.x, tid = threadIdx.x;
  __shared__ float xg[B_][KIPP];
  __shared__ float wm[O][36];
  __shared__ float es[ED_];
  if (tid < ED_) es[tid] = Ein[n*ED_ + tid];
  build4<LAYER, KIP, KIPP>(xg, p0, p1, p2, p3, n, t, tid);
  __syncthreads();
  const int isbf = flag[0];
  float el[ED_];
#pragma unroll
  for (int d = 0; d < ED_; ++d) el[d] = es[d];

  const int b = tid >> 4, q = tid & 15;
  float acc[4];
#pragma unroll
  for (int j = 0; j < 4; ++j) acc[j] = 0.f;

  for (int k0 = 0; k0 < KIP; k0 += 32) {
#pragma unroll
    for (int i = 0; i < O*8/256; ++i) {
      const int idx = tid + i*256;
      const int o = idx >> 3, kq = (idx & 7) * 4;
      const float4 a4 = merge_w<O, KIP>(WbF, WbH, el, o, k0 + kq, isbf);
      *(float4*)&wm[o][kq] = a4;
    }
    __syncthreads();
#pragma unroll
    for (int kq = 0; kq < 8; ++kq) {
      const float4 xv = *(const float4*)&xg[b][k0 + kq*4];
#pragma unroll
      for (int j = 0; j < 4; ++j) {
        const float4 wv = *(const float4*)&wm[q + 16*j][kq*4];
        acc[j] += xv.x*wv.x + xv.y*wv.y + xv.z*wv.z + xv.w*wv.w;
      }
    }
    __syncthreads();
  }
#pragma unroll
  for (int j = 0; j < 4; ++j) {
    const int o = q + 16*j;
    const float hc = tanhf(acc[j] + buv[n*64 + o]);
    const float rr = r_buf[(size_t)n*BH + b*64 + o];
    const float hold = hstate[(size_t)n*BH + b*64 + o];
    hstate[(size_t)n*BH + b*64 + o] = rr*hold + (1.f - rr)*hc;
  }
}

__global__ void k_zero_f(float* __restrict__ p, int n) {
  const int i = blockIdx.x*256 + threadIdx.x;
  if (i < n) p[i] = 0.f;
}
__global__ void k_zero_out(void* __restrict__ out, int nelem,
                           const int* __restrict__ flag) {
  const int i = blockIdx.x*256 + threadIdx.x;
  if (i < nelem) {
    if (flag[0]) ((unsigned short*)out)[i] = 0;
    else         ((float*)out)[i] = 0.f;
  }
}

// out[b][hor][n] = sum_c h2[n][b*64+c]*cwf[hor][c] + cbf[hor]
__global__ __launch_bounds__(256) void k_conv(const float* __restrict__ h2,
                                              const float* __restrict__ cwf,
                                              const float* __restrict__ cbf,
                                              void* __restrict__ out,
                                              const int* __restrict__ flag) {
  const int n = blockIdx.x, tid = threadIdx.x;
  __shared__ float hs[BH];
  for (int i = tid; i < BH; i += 256) hs[i] = h2[(size_t)n*BH + i];
  __syncthreads();
  const int isbf = flag[0];
  for (int i = tid; i < B_*HOR_; i += 256) {
    const int b = i / HOR_, hor = i - b*HOR_;
    float acc = cbf[hor];
#pragma unroll
    for (int c = 0; c < HID_; ++c) acc += hs[b*HID_ + c]*cwf[hor*HID_ + c];
    const size_t oi = (size_t)(b*HOR_ + hor)*N_ + n;
    if (isbf) ((bf16*)out)[oi] = f2b(acc);
    else      ((float*)out)[oi] = acc;
  }
}

// ---------------------------------------------------------------------------
extern "C" void kernel_launch(void* const* d_in, const int* in_sizes, int n_in,
                              void* d_out, int out_size, void* d_ws, size_t ws_size,
                              hipStream_t stream) {
  const void* src = d_in[0];
  const void* E   = d_in[1];
  const void* Wg0 = d_in[2];
  const void* bg0 = d_in[3];
  const void* Wu0 = d_in[4];
  const void* bu0 = d_in[5];
  const void* Wg1 = d_in[6];
  const void* bg1 = d_in[7];
  const void* Wu1 = d_in[8];
  const void* bu1 = d_in[9];
  const void* cw  = d_in[10];
  const void* cb  = d_in[11];
  (void)in_sizes; (void)n_in;

  char* p = (char*)d_ws;
  auto alloc = [&](size_t bytes) -> char* {
    char* r = p; p += (bytes + 255) & ~(size_t)255; return r;
  };
  const size_t SL = (size_t)N_*BH;
  int*   flag  = (int*)  alloc(256);
  float* Ein   = (float*)alloc((size_t)N_*ED_*4);
  float* cwf   = (float*)alloc((size_t)HOR_*HID_*4);
  float* cbf   = (float*)alloc((size_t)HOR_*4);
  float* S_f   = (float*)alloc((size_t)N_*N_*4);
  float* Wg0F  = (float*)alloc((size_t)ED_*128*160*4);
  float* Wu0F  = (float*)alloc((size_t)ED_*64*160*4);
  float* Wg1F  = (float*)alloc((size_t)ED_*128*256*4);
  float* Wu1F  = (float*)alloc((size_t)ED_*64*256*4);
  bf16*  Wg0H  = (bf16*) alloc((size_t)ED_*128*160*2);
  bf16*  Wu0H  = (bf16*) alloc((size_t)ED_*64*160*2);
  bf16*  Wg1H  = (bf16*) alloc((size_t)ED_*128*256*2);
  bf16*  Wu1H  = (bf16*) alloc((size_t)ED_*64*256*2);
  float* bgv0  = (float*)alloc((size_t)N_*128*4);
  float* buv0  = (float*)alloc((size_t)N_*64*4);
  float* bgv1  = (float*)alloc((size_t)N_*128*4);
  float* buv1  = (float*)alloc((size_t)N_*64*4);
  float* srcf  = (float*)alloc((size_t)BT*N_*4);
  float* Sx0   = (float*)alloc((size_t)N_*BT*4);
  float* h0    = (float*)alloc(SL*4);              // h0,h2 adjacent (one zero)
  float* h2    = (float*)alloc(SL*4);
  float* Sh_a  = (float*)alloc(SL*4);              // Sh_a,Sh_b adjacent
  float* Sh_b  = (float*)alloc(SL*4);              // Sh_b doubles as Szh buf
  float* zh    = (float*)alloc(SL*4);
  float* r_buf = (float*)alloc(SL*4);

  auto cdiv = [](int a, int b) { return (a + b - 1) / b; };

  k_detect<<<dim3(1), 256, 0, stream>>>(E, flag);

  const size_t required = (size_t)(p - (char*)d_ws);
  if (required > ws_size) {
    k_zero_out<<<dim3(cdiv(out_size, 256)), 256, 0, stream>>>(d_out, out_size, flag);
    return;
  }

  // --- casts + setup ---
  k_castE  <<<dim3(cdiv(N_*ED_, 256)), 256, 0, stream>>>(E, Ein, flag);
  k_castsrc<<<dim3(cdiv(BT*N_, 256)),  256, 0, stream>>>(src, srcf, flag);
  k_castc  <<<dim3(cdiv(HOR_*HID_, 256)), 256, 0, stream>>>(cw, cb, cwf, cbf, flag);
  k_prepT<0><<<dim3(cdiv(ED_*128*160, 256)), 256, 0, stream>>>(Wg0, Wg0F, Wg0H, 65, 160, 128, flag);
  k_prepT<0><<<dim3(cdiv(ED_*64*160,  256)), 256, 0, stream>>>(Wu0, Wu0F, Wu0H, 65, 160, 64, flag);
  k_prepT<1><<<dim3(cdiv(ED_*128*256, 256)), 256, 0, stream>>>(Wg1, Wg1F, Wg1H, 128, 256, 128, flag);
  k_prepT<1><<<dim3(cdiv(ED_*64*256,  256)), 256, 0, stream>>>(Wu1, Wu1F, Wu1H, 128, 256, 64, flag);
  k_matb<<<dim3(N_), 128, 0, stream>>>(Ein, bg0, bgv0, 128, flag);
  k_matb<<<dim3(N_), 128, 0, stream>>>(Ein, bu0, buv0, 64,  flag);
  k_matb<<<dim3(N_), 128, 0, stream>>>(Ein, bg1, bgv1, 128, flag);
  k_matb<<<dim3(N_), 128, 0, stream>>>(Ein, bu1, buv1, 64,  flag);
  k_softmax_S<<<dim3(N_), 256, 0, stream>>>(Ein, S_f);

  // Sx0[n, bt] = sum_m S[n,m]*srcf[bt*N + m]
  k_gemm64T<<<dim3(N_/64, BT/64), 256, 0, stream>>>(S_f, srcf, Sx0, N_, BT);

  // zero recurrent states + Sh_a/Sh_b (adjacent pairs)
  k_zero_f<<<dim3((int)((2*SL + 255)/256)), 256, 0, stream>>>(h0, (int)(2*SL));
  k_zero_f<<<dim3((int)((2*SL + 255)/256)), 256, 0, stream>>>(Sh_a, (int)(2*SL));

  // --- t = 0 (states zero: Sh terms vanish except S@h1[0]) ---
  k_gateW<0,160><<<dim3(N_), 256, 0, stream>>>(Wg0F, Wg0H, bgv0, h0, srcf, Sh_a, Sx0,
                                               Ein, h0, zh, r_buf, flag, 0);
  k_candW<0,160><<<dim3(N_), 256, 0, stream>>>(Wu0F, Wu0H, buv0, zh, srcf, Sh_b, Sx0,
                                               Ein, r_buf, h0, flag, 0);
  // Sh_a (zeroed) += S@h1[0]
  k_gemm8<<<dim3(N_/128, BH/128, KS), 256, 0, stream>>>(S_f, h0, Sh_a, BH, BH,
                                                        h0, Sh_a, BH, BH, 1 << 30);
  k_gateW<1,256><<<dim3(N_), 256, 0, stream>>>(Wg1F, Wg1H, bgv1, h0, h2, Sh_a, Sh_b,
                                               Ein, h2, zh, r_buf, flag, 0);
  k_candW<1,256><<<dim3(N_), 256, 0, stream>>>(Wu1F, Wu1H, buv1, h0, zh, Sh_a, Sh_b,
                                               Ein, r_buf, h2, flag, 0);

  // --- t >= 1: Sh_a from previous step's dual GEMM serves L0's S@h ---
  for (int t = 1; t < T_; ++t) {
    k_gateW<0,160><<<dim3(N_), 256, 0, stream>>>(Wg0F, Wg0H, bgv0, h0, srcf, Sh_a, Sx0,
                                                 Ein, h0, zh, r_buf, flag, t);
    // Szh0 -> Sh_b
    k_zero_f<<<dim3((int)((SL + 255)/256)), 256, 0, stream>>>(Sh_b, (int)SL);
    k_gemm8<<<dim3(N_/128, BH/128, KS), 256, 0, stream>>>(S_f, zh, Sh_b, BH, BH,
                                                          zh, Sh_b, BH, BH, 1 << 30);
    k_candW<0,160><<<dim3(N_), 256, 0, stream>>>(Wu0F, Wu0H, buv0, zh, srcf, Sh_b, Sx0,
                                                 Ein, r_buf, h0, flag, t);
    // h0 now holds h1[:, t]; dual: Sh_a = S@h1t, Sh_b = S@h2
    k_zero_f<<<dim3((int)((2*SL + 255)/256)), 256, 0, stream>>>(Sh_a, (int)(2*SL));
    k_gemm8<<<dim3(N_/128, 2*BH/128, KS), 256, 0, stream>>>(S_f, h0, Sh_a, BH, BH,
                                                            h2, Sh_b, BH, BH, BH);
    k_gateW<1,256><<<dim3(N_), 256, 0, stream>>>(Wg1F, Wg1H, bgv1, h0, h2, Sh_a, Sh_b,
                                                 Ein, h2, zh, r_buf, flag, t);
    // Szh1 -> Sh_b
    k_zero_f<<<dim3((int)((SL + 255)/256)), 256, 0, stream>>>(Sh_b, (int)SL);
    k_gemm8<<<dim3(N_/128, BH/128, KS), 256, 0, stream>>>(S_f, zh, Sh_b, BH, BH,
                                                          zh, Sh_b, BH, BH, 1 << 30);
    k_candW<1,256><<<dim3(N_), 256, 0, stream>>>(Wu1F, Wu1H, buv1, h0, zh, Sh_a, Sh_b,
                                                 Ein, r_buf, h2, flag, t);
  }

  // --- final conv ---
  k_conv<<<dim3(N_), 256, 0, stream>>>(h2, cwf, cbf, d_out, flag);
}

// Round 11
// 13993.953 us; speedup vs baseline: 1.0940x; 1.0940x over previous
//
#include <hip/hip_runtime.h>
#include <hip/hip_bf16.h>

// FP32-intermediate pipeline (recurrence is chaotic; bf16 rounding decorrelates).
// R11: GEMM = 128x64 tile, 8x4 micro (0.75 B/FLOP, VALU-ceiling ~62%), TK=16,
//      split-k=4 atomics. Dual grid 2048 blocks (8/CU) restores R9's latency
//      hiding at R10's arithmetic intensity.

#define B_    16
#define T_    12
#define N_    2048
#define HID_  64
#define ED_   10
#define HOR_  12
#define BH    (B_*HID_)    // 1024
#define BT    (B_*T_)      // 192
#define KS    4            // split-k slices
#define MSL   (N_/KS)      // 512 m's per slice

typedef __hip_bfloat16 bf16;
__device__ __forceinline__ float b2f(bf16 x){ return __bfloat162float(x); }
__device__ __forceinline__ bf16  f2b(float x){ return __float2bfloat16(x); }
__device__ __forceinline__ float bits2f(unsigned u) {
  union { float f; unsigned i; } c; c.i = u << 16; return c.f;
}

__device__ __forceinline__ float ldin(const void* p, size_t i, int isbf) {
  return isbf ? b2f(((const bf16*)p)[i]) : ((const float*)p)[i];
}
__device__ __forceinline__ void fma4(float4& a, float s, const float4& b) {
  a.x += s*b.x; a.y += s*b.y; a.z += s*b.z; a.w += s*b.w;
}

// ---------------------------------------------------------------------------
// dtype detector on E (bits 14:7 of 32-bit words: bf16 exponent vs mantissa)
// ---------------------------------------------------------------------------
__global__ void k_detect(const void* __restrict__ E, int* __restrict__ flag) {
  __shared__ int cnt;
  if (threadIdx.x == 0) cnt = 0;
  __syncthreads();
  const unsigned* w = (const unsigned*)E;
  int c = 0;
  for (int i = threadIdx.x; i < 4096; i += 256) {
    const unsigned e = (w[i] >> 7) & 0xFFu;
    if (e >= 0x6Eu && e <= 0x86u) ++c;
  }
  atomicAdd(&cnt, c);
  __syncthreads();
  if (threadIdx.x == 0) flag[0] = (cnt > 2048) ? 1 : 0;
}

// --- input casts to fp32 internal buffers ---
__global__ void k_castE(const void* __restrict__ E, float* __restrict__ Ein,
                        const int* __restrict__ flag) {
  const int i = blockIdx.x*256 + threadIdx.x;
  if (i < N_*ED_) Ein[i] = ldin(E, i, flag[0]);
}
__global__ void k_castsrc(const void* __restrict__ src, float* __restrict__ srcf,
                          const int* __restrict__ flag) {
  const int i = blockIdx.x*256 + threadIdx.x;
  if (i < B_*T_*N_) srcf[i] = ldin(src, i, flag[0]);
}
__global__ void k_castc(const void* __restrict__ cw, const void* __restrict__ cb,
                        float* __restrict__ cwf, float* __restrict__ cbf,
                        const int* __restrict__ flag) {
  const int i = blockIdx.x*256 + threadIdx.x;
  const int f = flag[0];
  if (i < HOR_*HID_) cwf[i] = ldin(cw, i, f);
  if (i < HOR_)      cbf[i] = ldin(cb, i, f);
}

// ---------------------------------------------------------------------------
// S = softmax(relu(Ein @ Ein^T), axis=1) -> fp32 row-major
// ---------------------------------------------------------------------------
__global__ __launch_bounds__(256) void k_softmax_S(const float* __restrict__ Ein,
                                                   float* __restrict__ S) {
  const int n = blockIdx.x, tid = threadIdx.x;
  __shared__ float er[ED_];
  __shared__ float red[4];
  if (tid < ED_) er[tid] = Ein[n*ED_ + tid];
  __syncthreads();
  float e[ED_];
#pragma unroll
  for (int d = 0; d < ED_; ++d) e[d] = er[d];
  float v[8];
  float mx = 0.f;
#pragma unroll
  for (int j = 0; j < 8; ++j) {
    const int m = tid + j*256;
    float dot = 0.f;
#pragma unroll
    for (int d = 0; d < ED_; ++d) dot += e[d]*Ein[m*ED_ + d];
    v[j] = fmaxf(dot, 0.f);
    mx = fmaxf(mx, v[j]);
  }
  for (int o = 32; o; o >>= 1) mx = fmaxf(mx, __shfl_xor(mx, o, 64));
  if ((tid & 63) == 0) red[tid >> 6] = mx;
  __syncthreads();
  mx = fmaxf(fmaxf(red[0], red[1]), fmaxf(red[2], red[3]));
  __syncthreads();
  float sum = 0.f;
#pragma unroll
  for (int j = 0; j < 8; ++j) { v[j] = __expf(v[j] - mx); sum += v[j]; }
  for (int o = 32; o; o >>= 1) sum += __shfl_xor(sum, o, 64);
  if ((tid & 63) == 0) red[tid >> 6] = sum;
  __syncthreads();
  sum = red[0] + red[1] + red[2] + red[3];
  const float inv = 1.f / sum;
#pragma unroll
  for (int j = 0; j < 8; ++j)
    S[(size_t)n*N_ + tid + j*256] = v[j]*inv;
}

// ---------------------------------------------------------------------------
// Basis weights, transposed + K-remapped: fp32 AND bf16 copies.
// LAYER0 (KIin=65,KIP=160): kp<64 ->(cheb0,kp+1); kp==64 ->(cheb0,0);
//   80<=kp<144 ->(cheb1,kp-79); kp==144 ->(cheb1,0); else 0.
// LAYER1 (KIin=128,KIP=256): cheb=kp>>7, i=kp&127.
// ---------------------------------------------------------------------------
template<int LAYER>
__global__ __launch_bounds__(256) void k_prepT(const void* __restrict__ Wb,
                                               float* __restrict__ WbF,
                                               bf16* __restrict__ WbH,
                                               int KIin, int KIP, int O,
                                               const int* __restrict__ flag) {
  const int idx = blockIdx.x*256 + threadIdx.x;
  if (idx >= ED_*O*KIP) return;
  const int d = idx / (O*KIP), rem = idx - d*O*KIP;
  const int o = rem / KIP, kp = rem - o*KIP;
  int cheb, i; bool valid;
  if (LAYER == 0) {
    cheb = (kp >= 80) ? 1 : 0;
    const int local = kp - cheb*80;
    if (local < 64)       { i = local + 1; valid = true; }
    else if (local == 64) { i = 0;         valid = true; }
    else                  { i = 0;         valid = false; }
  } else {
    cheb = kp >> 7; i = kp & 127; valid = true;
  }
  float v = 0.f;
  if (valid) v = ldin(Wb, (size_t)((d*2 + cheb)*KIin + i)*O + o, flag[0]);
  WbF[(size_t)(d*O + o)*KIP + kp] = v;
  WbH[(size_t)(d*O + o)*KIP + kp] = f2b(v);   // exact in bf16-world
}

// bias vectors: outv[n][o] = sum_d Ein[n,d]*bb[d][o]
__global__ __launch_bounds__(128) void k_matb(const float* __restrict__ Ein,
                                              const void* __restrict__ bb,
                                              float* __restrict__ outv, int O,
                                              const int* __restrict__ flag) {
  const int n = blockIdx.x, tid = threadIdx.x;
  if (tid >= O) return;
  const int f = flag[0];
  float acc = 0.f;
#pragma unroll
  for (int d = 0; d < ED_; ++d) acc += Ein[n*ED_ + d]*ldin(bb, d*O + tid, f);
  outv[n*O + tid] = acc;
}

// ---------------------------------------------------------------------------
// Small 64-tile GEMM for Sx0 only (XT form: X[c*ldx+m]); cols = BT = 192
// ---------------------------------------------------------------------------
__global__ __launch_bounds__(256) void k_gemm64T(const float* __restrict__ S,
                                                 const float* __restrict__ X,
                                                 float* __restrict__ C,
                                                 int ldx, int ldc) {
  const int bm = blockIdx.x * 64;
  const int bc = blockIdx.y * 64;
  __shared__ float St[64][68];
  __shared__ float Xt[64][68];
  const int tid = threadIdx.x;
  const int r0 = (tid >> 4) * 4;
  const int c0 = (tid & 15) * 4;
  float acc[4][4];
#pragma unroll
  for (int i = 0; i < 4; ++i)
#pragma unroll
    for (int j = 0; j < 4; ++j) acc[i][j] = 0.f;
  for (int mk = 0; mk < N_; mk += 64) {
    {
      const int r = tid >> 2, ks = (tid & 3) * 16;
      const float* sp = S + (size_t)(bm + r)*N_ + mk + ks;
#pragma unroll
      for (int u = 0; u < 16; ++u) St[ks + u][r] = sp[u];
      const float* xp = X + (size_t)(bc + r)*ldx + mk + ks;
#pragma unroll
      for (int u = 0; u < 16; ++u) Xt[ks + u][r] = xp[u];
    }
    __syncthreads();
#pragma unroll 4
    for (int kk = 0; kk < 64; ++kk) {
      const float a0 = St[kk][r0], a1 = St[kk][r0+1],
                  a2 = St[kk][r0+2], a3 = St[kk][r0+3];
      const float b0 = Xt[kk][c0], b1 = Xt[kk][c0+1],
                  b2 = Xt[kk][c0+2], b3 = Xt[kk][c0+3];
      acc[0][0] += a0*b0; acc[0][1] += a0*b1; acc[0][2] += a0*b2; acc[0][3] += a0*b3;
      acc[1][0] += a1*b0; acc[1][1] += a1*b1; acc[1][2] += a1*b2; acc[1][3] += a1*b3;
      acc[2][0] += a2*b0; acc[2][1] += a2*b1; acc[2][2] += a2*b2; acc[2][3] += a2*b3;
      acc[3][0] += a3*b0; acc[3][1] += a3*b1; acc[3][2] += a3*b2; acc[3][3] += a3*b3;
    }
    __syncthreads();
  }
#pragma unroll
  for (int i = 0; i < 4; ++i)
#pragma unroll
    for (int j = 0; j < 4; ++j)
      C[(size_t)(bm + r0 + i)*ldc + bc + c0 + j] = acc[i][j];
}

// ---------------------------------------------------------------------------
// Main split-k GEMM: 128x64 tile, 8x4 micro (rows r0..+3 and r0+64..+67,
// cols c0..+3), TK=16. C(n,c) += sum_{m in slice z} S[n,m]*X[m*ldx+c].
// 0.75 B/FLOP LDS; VALU ceiling ~62%. Output PRE-ZEROED (atomicAdd epilogue).
// Grid: (N/128, cols/64, KS). Dual: blockIdx.y*64 >= split -> X2/C2 (rebased).
// ---------------------------------------------------------------------------
__global__ __launch_bounds__(256) void k_gemmW(const float* __restrict__ S,
                                               const float* __restrict__ X1,
                                               float* __restrict__ C1,
                                               int ldx1, int ldc1,
                                               const float* __restrict__ X2,
                                               float* __restrict__ C2,
                                               int ldx2, int ldc2,
                                               int split) {
  const int bm = blockIdx.x * 128;
  int bc = blockIdx.y * 64;
  const float* X = X1; float* C = C1; int ldx = ldx1, ldc = ldc1;
  if (bc >= split) { X = X2; C = C2; ldx = ldx2; ldc = ldc2; bc -= split; }
  const int mk0 = blockIdx.z * MSL;

  __shared__ float Ss[16][132];   // Ss[kk][r] = S[bm+r][mk+kk]  (8.4 KB)
  __shared__ float Xs[16][68];    // Xs[kk][c] = X[mk+kk][bc+c]  (4.4 KB)
  const int tid = threadIdx.x;
  const int r0 = (tid >> 4) * 4;  // rows r0..+3 and r0+64..+67
  const int c0 = (tid & 15) * 4;  // cols c0..+3

  float acc[2][4][4];
#pragma unroll
  for (int u = 0; u < 2; ++u)
#pragma unroll
    for (int i = 0; i < 4; ++i)
#pragma unroll
      for (int j = 0; j < 4; ++j) acc[u][i][j] = 0.f;

  for (int mk = mk0; mk < mk0 + MSL; mk += 16) {
    // stage S: 128 rows x 16 k = 512 float4 (2/thread, transposed scatter)
#pragma unroll
    for (int u = 0; u < 2; ++u) {
      const int idx = tid + u*256;
      const int r = idx >> 2, kq = (idx & 3) * 4;
      const float4 v4 = *(const float4*)(S + (size_t)(bm + r)*N_ + mk + kq);
      Ss[kq + 0][r] = v4.x; Ss[kq + 1][r] = v4.y;
      Ss[kq + 2][r] = v4.z; Ss[kq + 3][r] = v4.w;
    }
    // stage X: 16 k x 64 c = 256 float4 (1/thread, natural)
    {
      const int kk = tid >> 4, cq = (tid & 15) * 4;
      *(float4*)&Xs[kk][cq] = *(const float4*)(X + (size_t)(mk + kk)*ldx + bc + cq);
    }
    __syncthreads();
#pragma unroll
    for (int kk = 0; kk < 16; ++kk) {
      const float4 aA = *(const float4*)&Ss[kk][r0];
      const float4 aB = *(const float4*)&Ss[kk][r0 + 64];
      const float4 b4 = *(const float4*)&Xs[kk][c0];
      const float ar[2][4] = {{aA.x,aA.y,aA.z,aA.w},{aB.x,aB.y,aB.z,aB.w}};
      const float b[4] = {b4.x, b4.y, b4.z, b4.w};
#pragma unroll
      for (int u = 0; u < 2; ++u)
#pragma unroll
        for (int i = 0; i < 4; ++i)
#pragma unroll
          for (int j = 0; j < 4; ++j)
            acc[u][i][j] += ar[u][i]*b[j];
    }
    __syncthreads();
  }
#pragma unroll
  for (int u = 0; u < 2; ++u)
#pragma unroll
    for (int i = 0; i < 4; ++i)
#pragma unroll
      for (int j = 0; j < 4; ++j)
        atomicAdd(C + (size_t)(bm + r0 + i + 64*u)*ldc + bc + c0 + j,
                  acc[u][i][j]);
}

// ---------------------------------------------------------------------------
// xg builder (float4): xg[b][k], padded row stride KIPP.
// LAYER0 (KIP=160): k<64:h(p0); k==64:x(p1,(b*T+t)*N+n); [80,144):Sh(p2);
//   k==144:Sx(p3,n*BT+b*T+t); else 0.
// LAYER1 (KIP=256): [0,64)p0 |[64,128)p1 |[128,192)p2 |[192,256)p3, n-major.
// ---------------------------------------------------------------------------
template<int LAYER, int KIP, int KIPP>
__device__ __forceinline__ void build4(float (*xg)[KIPP],
                                       const float* p0, const float* p1,
                                       const float* p2, const float* p3,
                                       int n, int t, int tid) {
  constexpr int NQ = KIP/4;
  for (int idx = tid; idx < B_*NQ; idx += 256) {
    const int b = idx / NQ, k = (idx - b*NQ) * 4;
    float4 v = make_float4(0.f, 0.f, 0.f, 0.f);
    if (LAYER == 1) {
      const float* rg = (k < 64) ? p0 : (k < 128) ? p1 : (k < 192) ? p2 : p3;
      v = *(const float4*)(rg + (size_t)n*BH + b*64 + (k & 63));
    } else {
      if (k < 64)        v = *(const float4*)(p0 + (size_t)n*BH + b*64 + k);
      else if (k == 64)  v.x = p1[(size_t)(b*T_ + t)*N_ + n];
      else if (k >= 80 && k < 144)
                         v = *(const float4*)(p2 + (size_t)n*BH + b*64 + (k - 80));
      else if (k == 144) v.x = p3[(size_t)n*BT + b*T_ + t];
    }
    *(float4*)&xg[b][k] = v;
  }
}

// merge helper: wm-row accumulate, dtype-switched (uniform branch on isbf)
template<int O, int KIP>
__device__ __forceinline__ float4 merge_w(const float* WbF, const bf16* WbH,
                                          const float* el, int o, int kq,
                                          int isbf) {
  float4 a4 = make_float4(0.f, 0.f, 0.f, 0.f);
  if (isbf) {
    const bf16* wp = WbH + (size_t)o*KIP + kq;
#pragma unroll
    for (int d = 0; d < ED_; ++d) {
      const uint2 w2 = *(const uint2*)(wp + (size_t)d*O*KIP);
      a4.x += el[d]*bits2f(w2.x & 0xFFFFu);
      a4.y += el[d]*bits2f(w2.x >> 16);
      a4.z += el[d]*bits2f(w2.y & 0xFFFFu);
      a4.w += el[d]*bits2f(w2.y >> 16);
    }
  } else {
    const float* wp = WbF + (size_t)o*KIP + kq;
#pragma unroll
    for (int d = 0; d < ED_; ++d)
      fma4(a4, el[d], *(const float4*)(wp + (size_t)d*O*KIP));
  }
  return a4;
}

// ---------------------------------------------------------------------------
// Gate: y[b,o] = sigmoid(sum_d E[n,d]*(xg[b,:]@Wb[d][:,o]) + bgv[n,o]), O=128.
// ---------------------------------------------------------------------------
template<int LAYER, int KIP>
__global__ __launch_bounds__(256) void k_gateW(const float* __restrict__ WbF,
                                               const bf16* __restrict__ WbH,
                                               const float* __restrict__ bgv,
                                               const float* __restrict__ p0,
                                               const float* __restrict__ p1,
                                               const float* __restrict__ p2,
                                               const float* __restrict__ p3,
                                               const float* __restrict__ Ein,
                                               const float* __restrict__ hstate,
                                               float* __restrict__ zh,
                                               float* __restrict__ r_buf,
                                               const int* __restrict__ flag,
                                               int t) {
  constexpr int KIPP = KIP + 4;
  constexpr int O = 128;
  const int n = blockIdx.x, tid = threadIdx.x;
  __shared__ float xg[B_][KIPP];
  __shared__ float wm[O][36];
  __shared__ float es[ED_];
  if (tid < ED_) es[tid] = Ein[n*ED_ + tid];
  build4<LAYER, KIP, KIPP>(xg, p0, p1, p2, p3, n, t, tid);
  __syncthreads();
  const int isbf = flag[0];
  float el[ED_];
#pragma unroll
  for (int d = 0; d < ED_; ++d) el[d] = es[d];

  const int b = tid >> 4, q = tid & 15;
  float acc[8];
#pragma unroll
  for (int j = 0; j < 8; ++j) acc[j] = 0.f;

  for (int k0 = 0; k0 < KIP; k0 += 32) {
#pragma unroll
    for (int i = 0; i < O*8/256; ++i) {
      const int idx = tid + i*256;
      const int o = idx >> 3, kq = (idx & 7) * 4;
      const float4 a4 = merge_w<O, KIP>(WbF, WbH, el, o, k0 + kq, isbf);
      *(float4*)&wm[o][kq] = a4;
    }
    __syncthreads();
#pragma unroll
    for (int kq = 0; kq < 8; ++kq) {
      const float4 xv = *(const float4*)&xg[b][k0 + kq*4];
#pragma unroll
      for (int j = 0; j < 8; ++j) {
        const float4 wv = *(const float4*)&wm[q + 16*j][kq*4];
        acc[j] += xv.x*wv.x + xv.y*wv.y + xv.z*wv.z + xv.w*wv.w;
      }
    }
    __syncthreads();
  }
#pragma unroll
  for (int j = 0; j < 8; ++j) {
    const int o = q + 16*j;
    float s = acc[j] + bgv[n*128 + o];
    s = 1.f/(1.f + __expf(-s));
    if (o < HID_)
      zh[(size_t)n*BH + b*64 + o] = s*hstate[(size_t)n*BH + b*64 + o];
    else
      r_buf[(size_t)n*BH + b*64 + (o - HID_)] = s;
  }
}

// ---------------------------------------------------------------------------
// Candidate: hc = tanh(...); h = r*h + (1-r)*hc in place. O=64.
// ---------------------------------------------------------------------------
template<int LAYER, int KIP>
__global__ __launch_bounds__(256) void k_candW(const float* __restrict__ WbF,
                                               const bf16* __restrict__ WbH,
                                               const float* __restrict__ buv,
                                               const float* __restrict__ p0,
                                               const float* __restrict__ p1,
                                               const float* __restrict__ p2,
                                               const float* __restrict__ p3,
                                               const float* __restrict__ Ein,
                                               const float* __restrict__ r_buf,
                                               float* __restrict__ hstate,
                                               const int* __restrict__ flag,
                                               int t) {
  constexpr int KIPP = KIP + 4;
  constexpr int O = 64;
  const int n = blockIdx.x, tid = threadIdx.x;
  __shared__ float xg[B_][KIPP];
  __shared__ float wm[O][36];
  __shared__ float es[ED_];
  if (tid < ED_) es[tid] = Ein[n*ED_ + tid];
  build4<LAYER, KIP, KIPP>(xg, p0, p1, p2, p3, n, t, tid);
  __syncthreads();
  const int isbf = flag[0];
  float el[ED_];
#pragma unroll
  for (int d = 0; d < ED_; ++d) el[d] = es[d];

  const int b = tid >> 4, q = tid & 15;
  float acc[4];
#pragma unroll
  for (int j = 0; j < 4; ++j) acc[j] = 0.f;

  for (int k0 = 0; k0 < KIP; k0 += 32) {
#pragma unroll
    for (int i = 0; i < O*8/256; ++i) {
      const int idx = tid + i*256;
      const int o = idx >> 3, kq = (idx & 7) * 4;
      const float4 a4 = merge_w<O, KIP>(WbF, WbH, el, o, k0 + kq, isbf);
      *(float4*)&wm[o][kq] = a4;
    }
    __syncthreads();
#pragma unroll
    for (int kq = 0; kq < 8; ++kq) {
      const float4 xv = *(const float4*)&xg[b][k0 + kq*4];
#pragma unroll
      for (int j = 0; j < 4; ++j) {
        const float4 wv = *(const float4*)&wm[q + 16*j][kq*4];
        acc[j] += xv.x*wv.x + xv.y*wv.y + xv.z*wv.z + xv.w*wv.w;
      }
    }
    __syncthreads();
  }
#pragma unroll
  for (int j = 0; j < 4; ++j) {
    const int o = q + 16*j;
    const float hc = tanhf(acc[j] + buv[n*64 + o]);
    const float rr = r_buf[(size_t)n*BH + b*64 + o];
    const float hold = hstate[(size_t)n*BH + b*64 + o];
    hstate[(size_t)n*BH + b*64 + o] = rr*hold + (1.f - rr)*hc;
  }
}

__global__ void k_zero_f(float* __restrict__ p, int n) {
  const int i = blockIdx.x*256 + threadIdx.x;
  if (i < n) p[i] = 0.f;
}
__global__ void k_zero_out(void* __restrict__ out, int nelem,
                           const int* __restrict__ flag) {
  const int i = blockIdx.x*256 + threadIdx.x;
  if (i < nelem) {
    if (flag[0]) ((unsigned short*)out)[i] = 0;
    else         ((float*)out)[i] = 0.f;
  }
}

// out[b][hor][n] = sum_c h2[n][b*64+c]*cwf[hor][c] + cbf[hor]
__global__ __launch_bounds__(256) void k_conv(const float* __restrict__ h2,
                                              const float* __restrict__ cwf,
                                              const float* __restrict__ cbf,
                                              void* __restrict__ out,
                                              const int* __restrict__ flag) {
  const int n = blockIdx.x, tid = threadIdx.x;
  __shared__ float hs[BH];
  for (int i = tid; i < BH; i += 256) hs[i] = h2[(size_t)n*BH + i];
  __syncthreads();
  const int isbf = flag[0];
  for (int i = tid; i < B_*HOR_; i += 256) {
    const int b = i / HOR_, hor = i - b*HOR_;
    float acc = cbf[hor];
#pragma unroll
    for (int c = 0; c < HID_; ++c) acc += hs[b*HID_ + c]*cwf[hor*HID_ + c];
    const size_t oi = (size_t)(b*HOR_ + hor)*N_ + n;
    if (isbf) ((bf16*)out)[oi] = f2b(acc);
    else      ((float*)out)[oi] = acc;
  }
}

// ---------------------------------------------------------------------------
extern "C" void kernel_launch(void* const* d_in, const int* in_sizes, int n_in,
                              void* d_out, int out_size, void* d_ws, size_t ws_size,
                              hipStream_t stream) {
  const void* src = d_in[0];
  const void* E   = d_in[1];
  const void* Wg0 = d_in[2];
  const void* bg0 = d_in[3];
  const void* Wu0 = d_in[4];
  const void* bu0 = d_in[5];
  const void* Wg1 = d_in[6];
  const void* bg1 = d_in[7];
  const void* Wu1 = d_in[8];
  const void* bu1 = d_in[9];
  const void* cw  = d_in[10];
  const void* cb  = d_in[11];
  (void)in_sizes; (void)n_in;

  char* p = (char*)d_ws;
  auto alloc = [&](size_t bytes) -> char* {
    char* r = p; p += (bytes + 255) & ~(size_t)255; return r;
  };
  const size_t SL = (size_t)N_*BH;
  int*   flag  = (int*)  alloc(256);
  float* Ein   = (float*)alloc((size_t)N_*ED_*4);
  float* cwf   = (float*)alloc((size_t)HOR_*HID_*4);
  float* cbf   = (float*)alloc((size_t)HOR_*4);
  float* S_f   = (float*)alloc((size_t)N_*N_*4);
  float* Wg0F  = (float*)alloc((size_t)ED_*128*160*4);
  float* Wu0F  = (float*)alloc((size_t)ED_*64*160*4);
  float* Wg1F  = (float*)alloc((size_t)ED_*128*256*4);
  float* Wu1F  = (float*)alloc((size_t)ED_*64*256*4);
  bf16*  Wg0H  = (bf16*) alloc((size_t)ED_*128*160*2);
  bf16*  Wu0H  = (bf16*) alloc((size_t)ED_*64*160*2);
  bf16*  Wg1H  = (bf16*) alloc((size_t)ED_*128*256*2);
  bf16*  Wu1H  = (bf16*) alloc((size_t)ED_*64*256*2);
  float* bgv0  = (float*)alloc((size_t)N_*128*4);
  float* buv0  = (float*)alloc((size_t)N_*64*4);
  float* bgv1  = (float*)alloc((size_t)N_*128*4);
  float* buv1  = (float*)alloc((size_t)N_*64*4);
  float* srcf  = (float*)alloc((size_t)BT*N_*4);
  float* Sx0   = (float*)alloc((size_t)N_*BT*4);
  float* h0    = (float*)alloc(SL*4);              // h0,h2 adjacent (one zero)
  float* h2    = (float*)alloc(SL*4);
  float* Sh_a  = (float*)alloc(SL*4);              // Sh_a,Sh_b adjacent
  float* Sh_b  = (float*)alloc(SL*4);              // Sh_b doubles as Szh buf
  float* zh    = (float*)alloc(SL*4);
  float* r_buf = (float*)alloc(SL*4);

  auto cdiv = [](int a, int b) { return (a + b - 1) / b; };

  k_detect<<<dim3(1), 256, 0, stream>>>(E, flag);

  const size_t required = (size_t)(p - (char*)d_ws);
  if (required > ws_size) {
    k_zero_out<<<dim3(cdiv(out_size, 256)), 256, 0, stream>>>(d_out, out_size, flag);
    return;
  }

  // --- casts + setup ---
  k_castE  <<<dim3(cdiv(N_*ED_, 256)), 256, 0, stream>>>(E, Ein, flag);
  k_castsrc<<<dim3(cdiv(BT*N_, 256)),  256, 0, stream>>>(src, srcf, flag);
  k_castc  <<<dim3(cdiv(HOR_*HID_, 256)), 256, 0, stream>>>(cw, cb, cwf, cbf, flag);
  k_prepT<0><<<dim3(cdiv(ED_*128*160, 256)), 256, 0, stream>>>(Wg0, Wg0F, Wg0H, 65, 160, 128, flag);
  k_prepT<0><<<dim3(cdiv(ED_*64*160,  256)), 256, 0, stream>>>(Wu0, Wu0F, Wu0H, 65, 160, 64, flag);
  k_prepT<1><<<dim3(cdiv(ED_*128*256, 256)), 256, 0, stream>>>(Wg1, Wg1F, Wg1H, 128, 256, 128, flag);
  k_prepT<1><<<dim3(cdiv(ED_*64*256,  256)), 256, 0, stream>>>(Wu1, Wu1F, Wu1H, 128, 256, 64, flag);
  k_matb<<<dim3(N_), 128, 0, stream>>>(Ein, bg0, bgv0, 128, flag);
  k_matb<<<dim3(N_), 128, 0, stream>>>(Ein, bu0, buv0, 64,  flag);
  k_matb<<<dim3(N_), 128, 0, stream>>>(Ein, bg1, bgv1, 128, flag);
  k_matb<<<dim3(N_), 128, 0, stream>>>(Ein, bu1, buv1, 64,  flag);
  k_softmax_S<<<dim3(N_), 256, 0, stream>>>(Ein, S_f);

  // Sx0[n, bt] = sum_m S[n,m]*srcf[bt*N + m]
  k_gemm64T<<<dim3(N_/64, BT/64), 256, 0, stream>>>(S_f, srcf, Sx0, N_, BT);

  // zero recurrent states + Sh_a/Sh_b (adjacent pairs)
  k_zero_f<<<dim3((int)((2*SL + 255)/256)), 256, 0, stream>>>(h0, (int)(2*SL));
  k_zero_f<<<dim3((int)((2*SL + 255)/256)), 256, 0, stream>>>(Sh_a, (int)(2*SL));

  // --- t = 0 (states zero: Sh terms vanish except S@h1[0]) ---
  k_gateW<0,160><<<dim3(N_), 256, 0, stream>>>(Wg0F, Wg0H, bgv0, h0, srcf, Sh_a, Sx0,
                                               Ein, h0, zh, r_buf, flag, 0);
  k_candW<0,160><<<dim3(N_), 256, 0, stream>>>(Wu0F, Wu0H, buv0, zh, srcf, Sh_b, Sx0,
                                               Ein, r_buf, h0, flag, 0);
  // Sh_a (zeroed) += S@h1[0]
  k_gemmW<<<dim3(N_/128, BH/64, KS), 256, 0, stream>>>(S_f, h0, Sh_a, BH, BH,
                                                       h0, Sh_a, BH, BH, 1 << 30);
  k_gateW<1,256><<<dim3(N_), 256, 0, stream>>>(Wg1F, Wg1H, bgv1, h0, h2, Sh_a, Sh_b,
                                               Ein, h2, zh, r_buf, flag, 0);
  k_candW<1,256><<<dim3(N_), 256, 0, stream>>>(Wu1F, Wu1H, buv1, h0, zh, Sh_a, Sh_b,
                                               Ein, r_buf, h2, flag, 0);

  // --- t >= 1: Sh_a from previous step's dual GEMM serves L0's S@h ---
  for (int t = 1; t < T_; ++t) {
    k_gateW<0,160><<<dim3(N_), 256, 0, stream>>>(Wg0F, Wg0H, bgv0, h0, srcf, Sh_a, Sx0,
                                                 Ein, h0, zh, r_buf, flag, t);
    // Szh0 -> Sh_b
    k_zero_f<<<dim3((int)((SL + 255)/256)), 256, 0, stream>>>(Sh_b, (int)SL);
    k_gemmW<<<dim3(N_/128, BH/64, KS), 256, 0, stream>>>(S_f, zh, Sh_b, BH, BH,
                                                         zh, Sh_b, BH, BH, 1 << 30);
    k_candW<0,160><<<dim3(N_), 256, 0, stream>>>(Wu0F, Wu0H, buv0, zh, srcf, Sh_b, Sx0,
                                                 Ein, r_buf, h0, flag, t);
    // h0 now holds h1[:, t]; dual: Sh_a = S@h1t, Sh_b = S@h2
    k_zero_f<<<dim3((int)((2*SL + 255)/256)), 256, 0, stream>>>(Sh_a, (int)(2*SL));
    k_gemmW<<<dim3(N_/128, 2*BH/64, KS), 256, 0, stream>>>(S_f, h0, Sh_a, BH, BH,
                                                           h2, Sh_b, BH, BH, BH);
    k_gateW<1,256><<<dim3(N_), 256, 0, stream>>>(Wg1F, Wg1H, bgv1, h0, h2, Sh_a, Sh_b,
                                                 Ein, h2, zh, r_buf, flag, t);
    // Szh1 -> Sh_b
    k_zero_f<<<dim3((int)((SL + 255)/256)), 256, 0, stream>>>(Sh_b, (int)SL);
    k_gemmW<<<dim3(N_/128, BH/64, KS), 256, 0, stream>>>(S_f, zh, Sh_b, BH, BH,
                                                         zh, Sh_b, BH, BH, 1 << 30);
    k_candW<1,256><<<dim3(N_), 256, 0, stream>>>(Wu1F, Wu1H, buv1, h0, zh, Sh_a, Sh_b,
                                                 Ein, r_buf, h2, flag, t);
  }

  // --- final conv ---
  k_conv<<<dim3(N_), 256, 0, stream>>>(h2, cwf, cbf, d_out, flag);
}

// Round 12
// 12509.286 us; speedup vs baseline: 1.2238x; 1.1187x over previous
//
#include <hip/hip_runtime.h>
#include <hip/hip_bf16.h>

// FP32-intermediate pipeline (recurrence is chaotic; bf16 rounding decorrelates).
// R12: consolidation. GEMM = R8's 64x64/TK32/4x4 direct-store (measured at its
//      57% FMA-issue ceiling; split-k atomics cost 262MB writes -> removed).
//      Schedule = R9's Sh_a reuse + t=0 skip (3 GEMMs/step, zero fills gone).
//      Weights = R10's bf16 merge (exact in bf16-world).

#define B_    16
#define T_    12
#define N_    2048
#define HID_  64
#define ED_   10
#define HOR_  12
#define BH    (B_*HID_)    // 1024
#define BT    (B_*T_)      // 192

typedef __hip_bfloat16 bf16;
__device__ __forceinline__ float b2f(bf16 x){ return __bfloat162float(x); }
__device__ __forceinline__ bf16  f2b(float x){ return __float2bfloat16(x); }
__device__ __forceinline__ float bits2f(unsigned u) {
  union { float f; unsigned i; } c; c.i = u << 16; return c.f;
}

__device__ __forceinline__ float ldin(const void* p, size_t i, int isbf) {
  return isbf ? b2f(((const bf16*)p)[i]) : ((const float*)p)[i];
}
__device__ __forceinline__ void fma4(float4& a, float s, const float4& b) {
  a.x += s*b.x; a.y += s*b.y; a.z += s*b.z; a.w += s*b.w;
}

// ---------------------------------------------------------------------------
// dtype detector on E (bits 14:7 of 32-bit words: bf16 exponent vs mantissa)
// ---------------------------------------------------------------------------
__global__ void k_detect(const void* __restrict__ E, int* __restrict__ flag) {
  __shared__ int cnt;
  if (threadIdx.x == 0) cnt = 0;
  __syncthreads();
  const unsigned* w = (const unsigned*)E;
  int c = 0;
  for (int i = threadIdx.x; i < 4096; i += 256) {
    const unsigned e = (w[i] >> 7) & 0xFFu;
    if (e >= 0x6Eu && e <= 0x86u) ++c;
  }
  atomicAdd(&cnt, c);
  __syncthreads();
  if (threadIdx.x == 0) flag[0] = (cnt > 2048) ? 1 : 0;
}

// --- input casts to fp32 internal buffers ---
__global__ void k_castE(const void* __restrict__ E, float* __restrict__ Ein,
                        const int* __restrict__ flag) {
  const int i = blockIdx.x*256 + threadIdx.x;
  if (i < N_*ED_) Ein[i] = ldin(E, i, flag[0]);
}
__global__ void k_castsrc(const void* __restrict__ src, float* __restrict__ srcf,
                          const int* __restrict__ flag) {
  const int i = blockIdx.x*256 + threadIdx.x;
  if (i < B_*T_*N_) srcf[i] = ldin(src, i, flag[0]);
}
__global__ void k_castc(const void* __restrict__ cw, const void* __restrict__ cb,
                        float* __restrict__ cwf, float* __restrict__ cbf,
                        const int* __restrict__ flag) {
  const int i = blockIdx.x*256 + threadIdx.x;
  const int f = flag[0];
  if (i < HOR_*HID_) cwf[i] = ldin(cw, i, f);
  if (i < HOR_)      cbf[i] = ldin(cb, i, f);
}

// ---------------------------------------------------------------------------
// S = softmax(relu(Ein @ Ein^T), axis=1) -> fp32 row-major
// ---------------------------------------------------------------------------
__global__ __launch_bounds__(256) void k_softmax_S(const float* __restrict__ Ein,
                                                   float* __restrict__ S) {
  const int n = blockIdx.x, tid = threadIdx.x;
  __shared__ float er[ED_];
  __shared__ float red[4];
  if (tid < ED_) er[tid] = Ein[n*ED_ + tid];
  __syncthreads();
  float e[ED_];
#pragma unroll
  for (int d = 0; d < ED_; ++d) e[d] = er[d];
  float v[8];
  float mx = 0.f;
#pragma unroll
  for (int j = 0; j < 8; ++j) {
    const int m = tid + j*256;
    float dot = 0.f;
#pragma unroll
    for (int d = 0; d < ED_; ++d) dot += e[d]*Ein[m*ED_ + d];
    v[j] = fmaxf(dot, 0.f);
    mx = fmaxf(mx, v[j]);
  }
  for (int o = 32; o; o >>= 1) mx = fmaxf(mx, __shfl_xor(mx, o, 64));
  if ((tid & 63) == 0) red[tid >> 6] = mx;
  __syncthreads();
  mx = fmaxf(fmaxf(red[0], red[1]), fmaxf(red[2], red[3]));
  __syncthreads();
  float sum = 0.f;
#pragma unroll
  for (int j = 0; j < 8; ++j) { v[j] = __expf(v[j] - mx); sum += v[j]; }
  for (int o = 32; o; o >>= 1) sum += __shfl_xor(sum, o, 64);
  if ((tid & 63) == 0) red[tid >> 6] = sum;
  __syncthreads();
  sum = red[0] + red[1] + red[2] + red[3];
  const float inv = 1.f / sum;
#pragma unroll
  for (int j = 0; j < 8; ++j)
    S[(size_t)n*N_ + tid + j*256] = v[j]*inv;
}

// ---------------------------------------------------------------------------
// Basis weights, transposed + K-remapped: fp32 AND bf16 copies.
// LAYER0 (KIin=65,KIP=160): kp<64 ->(cheb0,kp+1); kp==64 ->(cheb0,0);
//   80<=kp<144 ->(cheb1,kp-79); kp==144 ->(cheb1,0); else 0.
// LAYER1 (KIin=128,KIP=256): cheb=kp>>7, i=kp&127.
// ---------------------------------------------------------------------------
template<int LAYER>
__global__ __launch_bounds__(256) void k_prepT(const void* __restrict__ Wb,
                                               float* __restrict__ WbF,
                                               bf16* __restrict__ WbH,
                                               int KIin, int KIP, int O,
                                               const int* __restrict__ flag) {
  const int idx = blockIdx.x*256 + threadIdx.x;
  if (idx >= ED_*O*KIP) return;
  const int d = idx / (O*KIP), rem = idx - d*O*KIP;
  const int o = rem / KIP, kp = rem - o*KIP;
  int cheb, i; bool valid;
  if (LAYER == 0) {
    cheb = (kp >= 80) ? 1 : 0;
    const int local = kp - cheb*80;
    if (local < 64)       { i = local + 1; valid = true; }
    else if (local == 64) { i = 0;         valid = true; }
    else                  { i = 0;         valid = false; }
  } else {
    cheb = kp >> 7; i = kp & 127; valid = true;
  }
  float v = 0.f;
  if (valid) v = ldin(Wb, (size_t)((d*2 + cheb)*KIin + i)*O + o, flag[0]);
  WbF[(size_t)(d*O + o)*KIP + kp] = v;
  WbH[(size_t)(d*O + o)*KIP + kp] = f2b(v);   // exact in bf16-world
}

// bias vectors: outv[n][o] = sum_d Ein[n,d]*bb[d][o]
__global__ __launch_bounds__(128) void k_matb(const float* __restrict__ Ein,
                                              const void* __restrict__ bb,
                                              float* __restrict__ outv, int O,
                                              const int* __restrict__ flag) {
  const int n = blockIdx.x, tid = threadIdx.x;
  if (tid >= O) return;
  const int f = flag[0];
  float acc = 0.f;
#pragma unroll
  for (int d = 0; d < ED_; ++d) acc += Ein[n*ED_ + d]*ldin(bb, d*O + tid, f);
  outv[n*O + tid] = acc;
}

// ---------------------------------------------------------------------------
// Small 64-tile GEMM for Sx0 only (XT form: X[c*ldx+m]); cols = BT = 192
// ---------------------------------------------------------------------------
__global__ __launch_bounds__(256) void k_gemm64T(const float* __restrict__ S,
                                                 const float* __restrict__ X,
                                                 float* __restrict__ C,
                                                 int ldx, int ldc) {
  const int bm = blockIdx.x * 64;
  const int bc = blockIdx.y * 64;
  __shared__ float St[64][68];
  __shared__ float Xt[64][68];
  const int tid = threadIdx.x;
  const int r0 = (tid >> 4) * 4;
  const int c0 = (tid & 15) * 4;
  float acc[4][4];
#pragma unroll
  for (int i = 0; i < 4; ++i)
#pragma unroll
    for (int j = 0; j < 4; ++j) acc[i][j] = 0.f;
  for (int mk = 0; mk < N_; mk += 64) {
    {
      const int r = tid >> 2, ks = (tid & 3) * 16;
      const float* sp = S + (size_t)(bm + r)*N_ + mk + ks;
#pragma unroll
      for (int u = 0; u < 16; ++u) St[ks + u][r] = sp[u];
      const float* xp = X + (size_t)(bc + r)*ldx + mk + ks;
#pragma unroll
      for (int u = 0; u < 16; ++u) Xt[ks + u][r] = xp[u];
    }
    __syncthreads();
#pragma unroll 4
    for (int kk = 0; kk < 64; ++kk) {
      const float a0 = St[kk][r0], a1 = St[kk][r0+1],
                  a2 = St[kk][r0+2], a3 = St[kk][r0+3];
      const float b0 = Xt[kk][c0], b1 = Xt[kk][c0+1],
                  b2 = Xt[kk][c0+2], b3 = Xt[kk][c0+3];
      acc[0][0] += a0*b0; acc[0][1] += a0*b1; acc[0][2] += a0*b2; acc[0][3] += a0*b3;
      acc[1][0] += a1*b0; acc[1][1] += a1*b1; acc[1][2] += a1*b2; acc[1][3] += a1*b3;
      acc[2][0] += a2*b0; acc[2][1] += a2*b1; acc[2][2] += a2*b2; acc[2][3] += a2*b3;
      acc[3][0] += a3*b0; acc[3][1] += a3*b1; acc[3][2] += a3*b2; acc[3][3] += a3*b3;
    }
    __syncthreads();
  }
#pragma unroll
  for (int i = 0; i < 4; ++i)
#pragma unroll
    for (int j = 0; j < 4; ++j)
      C[(size_t)(bm + r0 + i)*ldc + bc + c0 + j] = acc[i][j];
}

// ---------------------------------------------------------------------------
// Main 64x64-tile fp32 GEMM (R8 lineage — measured at its 57% FMA-issue
// ceiling): C(n,c) = sum_m S[n,m] * X[m*ldx + c]. TK=32, 4x4 micro, direct
// store. Grid: (N/64, cols/64). Dual: blockIdx.y*64 >= split -> X2/C2.
// ---------------------------------------------------------------------------
__global__ __launch_bounds__(256) void k_gemm64D(const float* __restrict__ S,
                                                 const float* __restrict__ X1,
                                                 float* __restrict__ C1,
                                                 int ldx1, int ldc1,
                                                 const float* __restrict__ X2,
                                                 float* __restrict__ C2,
                                                 int ldx2, int ldc2,
                                                 int split) {
  const int bm = blockIdx.x * 64;
  int bc = blockIdx.y * 64;
  const float* X = X1; float* C = C1; int ldx = ldx1, ldc = ldc1;
  if (bc >= split) { X = X2; C = C2; ldx = ldx2; ldc = ldc2; bc -= split; }

  __shared__ float Ss[32][68];   // Ss[kk][r] = S[bm+r][mk+kk]
  __shared__ float Xs[32][68];   // Xs[kk][c] = X[mk+kk][bc+c]
  const int tid = threadIdx.x;
  const int r0 = (tid >> 4) * 4;
  const int c0 = (tid & 15) * 4;

  float acc[4][4];
#pragma unroll
  for (int i = 0; i < 4; ++i)
#pragma unroll
    for (int j = 0; j < 4; ++j) acc[i][j] = 0.f;

  for (int mk = 0; mk < N_; mk += 32) {
    // stage S: 64 rows x 32 k = 512 float4 (transposed scatter)
#pragma unroll
    for (int u = 0; u < 2; ++u) {
      const int idx = tid + u*256;
      const int r = idx >> 3, kq = (idx & 7) * 4;
      const float4 v4 = *(const float4*)(S + (size_t)(bm + r)*N_ + mk + kq);
      Ss[kq + 0][r] = v4.x; Ss[kq + 1][r] = v4.y;
      Ss[kq + 2][r] = v4.z; Ss[kq + 3][r] = v4.w;
    }
    // stage X: 32 k x 64 c = 512 float4 (natural)
#pragma unroll
    for (int u = 0; u < 2; ++u) {
      const int idx = tid + u*256;
      const int kk = idx >> 4, cq = (idx & 15) * 4;
      *(float4*)&Xs[kk][cq] = *(const float4*)(X + (size_t)(mk + kk)*ldx + bc + cq);
    }
    __syncthreads();
#pragma unroll 8
    for (int kk = 0; kk < 32; ++kk) {
      const float4 a4 = *(const float4*)&Ss[kk][r0];
      const float4 b4 = *(const float4*)&Xs[kk][c0];
      const float a[4] = {a4.x, a4.y, a4.z, a4.w};
      const float b[4] = {b4.x, b4.y, b4.z, b4.w};
#pragma unroll
      for (int i = 0; i < 4; ++i)
#pragma unroll
        for (int j = 0; j < 4; ++j) acc[i][j] += a[i]*b[j];
    }
    __syncthreads();
  }
#pragma unroll
  for (int i = 0; i < 4; ++i) {
    float4 o4;
    o4.x = acc[i][0]; o4.y = acc[i][1]; o4.z = acc[i][2]; o4.w = acc[i][3];
    *(float4*)(C + (size_t)(bm + r0 + i)*ldc + bc + c0) = o4;
  }
}

// ---------------------------------------------------------------------------
// xg builder (float4): xg[b][k], padded row stride KIPP.
// LAYER0 (KIP=160): k<64:h(p0); k==64:x(p1,(b*T+t)*N+n); [80,144):Sh(p2);
//   k==144:Sx(p3,n*BT+b*T+t); else 0.
// LAYER1 (KIP=256): [0,64)p0 |[64,128)p1 |[128,192)p2 |[192,256)p3, n-major.
// ---------------------------------------------------------------------------
template<int LAYER, int KIP, int KIPP>
__device__ __forceinline__ void build4(float (*xg)[KIPP],
                                       const float* p0, const float* p1,
                                       const float* p2, const float* p3,
                                       int n, int t, int tid) {
  constexpr int NQ = KIP/4;
  for (int idx = tid; idx < B_*NQ; idx += 256) {
    const int b = idx / NQ, k = (idx - b*NQ) * 4;
    float4 v = make_float4(0.f, 0.f, 0.f, 0.f);
    if (LAYER == 1) {
      const float* rg = (k < 64) ? p0 : (k < 128) ? p1 : (k < 192) ? p2 : p3;
      v = *(const float4*)(rg + (size_t)n*BH + b*64 + (k & 63));
    } else {
      if (k < 64)        v = *(const float4*)(p0 + (size_t)n*BH + b*64 + k);
      else if (k == 64)  v.x = p1[(size_t)(b*T_ + t)*N_ + n];
      else if (k >= 80 && k < 144)
                         v = *(const float4*)(p2 + (size_t)n*BH + b*64 + (k - 80));
      else if (k == 144) v.x = p3[(size_t)n*BT + b*T_ + t];
    }
    *(float4*)&xg[b][k] = v;
  }
}

// merge helper: wm-row accumulate, dtype-switched (uniform branch on isbf)
template<int O, int KIP>
__device__ __forceinline__ float4 merge_w(const float* WbF, const bf16* WbH,
                                          const float* el, int o, int kq,
                                          int isbf) {
  float4 a4 = make_float4(0.f, 0.f, 0.f, 0.f);
  if (isbf) {
    const bf16* wp = WbH + (size_t)o*KIP + kq;
#pragma unroll
    for (int d = 0; d < ED_; ++d) {
      const uint2 w2 = *(const uint2*)(wp + (size_t)d*O*KIP);
      a4.x += el[d]*bits2f(w2.x & 0xFFFFu);
      a4.y += el[d]*bits2f(w2.x >> 16);
      a4.z += el[d]*bits2f(w2.y & 0xFFFFu);
      a4.w += el[d]*bits2f(w2.y >> 16);
    }
  } else {
    const float* wp = WbF + (size_t)o*KIP + kq;
#pragma unroll
    for (int d = 0; d < ED_; ++d)
      fma4(a4, el[d], *(const float4*)(wp + (size_t)d*O*KIP));
  }
  return a4;
}

// ---------------------------------------------------------------------------
// Gate: y[b,o] = sigmoid(sum_d E[n,d]*(xg[b,:]@Wb[d][:,o]) + bgv[n,o]), O=128.
// ---------------------------------------------------------------------------
template<int LAYER, int KIP>
__global__ __launch_bounds__(256) void k_gateW(const float* __restrict__ WbF,
                                               const bf16* __restrict__ WbH,
                                               const float* __restrict__ bgv,
                                               const float* __restrict__ p0,
                                               const float* __restrict__ p1,
                                               const float* __restrict__ p2,
                                               const float* __restrict__ p3,
                                               const float* __restrict__ Ein,
                                               const float* __restrict__ hstate,
                                               float* __restrict__ zh,
                                               float* __restrict__ r_buf,
                                               const int* __restrict__ flag,
                                               int t) {
  constexpr int KIPP = KIP + 4;
  constexpr int O = 128;
  const int n = blockIdx.x, tid = threadIdx.x;
  __shared__ float xg[B_][KIPP];
  __shared__ float wm[O][36];
  __shared__ float es[ED_];
  if (tid < ED_) es[tid] = Ein[n*ED_ + tid];
  build4<LAYER, KIP, KIPP>(xg, p0, p1, p2, p3, n, t, tid);
  __syncthreads();
  const int isbf = flag[0];
  float el[ED_];
#pragma unroll
  for (int d = 0; d < ED_; ++d) el[d] = es[d];

  const int b = tid >> 4, q = tid & 15;
  float acc[8];
#pragma unroll
  for (int j = 0; j < 8; ++j) acc[j] = 0.f;

  for (int k0 = 0; k0 < KIP; k0 += 32) {
#pragma unroll
    for (int i = 0; i < O*8/256; ++i) {
      const int idx = tid + i*256;
      const int o = idx >> 3, kq = (idx & 7) * 4;
      const float4 a4 = merge_w<O, KIP>(WbF, WbH, el, o, k0 + kq, isbf);
      *(float4*)&wm[o][kq] = a4;
    }
    __syncthreads();
#pragma unroll
    for (int kq = 0; kq < 8; ++kq) {
      const float4 xv = *(const float4*)&xg[b][k0 + kq*4];
#pragma unroll
      for (int j = 0; j < 8; ++j) {
        const float4 wv = *(const float4*)&wm[q + 16*j][kq*4];
        acc[j] += xv.x*wv.x + xv.y*wv.y + xv.z*wv.z + xv.w*wv.w;
      }
    }
    __syncthreads();
  }
#pragma unroll
  for (int j = 0; j < 8; ++j) {
    const int o = q + 16*j;
    float s = acc[j] + bgv[n*128 + o];
    s = 1.f/(1.f + __expf(-s));
    if (o < HID_)
      zh[(size_t)n*BH + b*64 + o] = s*hstate[(size_t)n*BH + b*64 + o];
    else
      r_buf[(size_t)n*BH + b*64 + (o - HID_)] = s;
  }
}

// ---------------------------------------------------------------------------
// Candidate: hc = tanh(...); h = r*h + (1-r)*hc in place. O=64.
// ---------------------------------------------------------------------------
template<int LAYER, int KIP>
__global__ __launch_bounds__(256) void k_candW(const float* __restrict__ WbF,
                                               const bf16* __restrict__ WbH,
                                               const float* __restrict__ buv,
                                               const float* __restrict__ p0,
                                               const float* __restrict__ p1,
                                               const float* __restrict__ p2,
                                               const float* __restrict__ p3,
                                               const float* __restrict__ Ein,
                                               const float* __restrict__ r_buf,
                                               float* __restrict__ hstate,
                                               const int* __restrict__ flag,
                                               int t) {
  constexpr int KIPP = KIP + 4;
  constexpr int O = 64;
  const int n = blockIdx.x, tid = threadIdx.x;
  __shared__ float xg[B_][KIPP];
  __shared__ float wm[O][36];
  __shared__ float es[ED_];
  if (tid < ED_) es[tid] = Ein[n*ED_ + tid];
  build4<LAYER, KIP, KIPP>(xg, p0, p1, p2, p3, n, t, tid);
  __syncthreads();
  const int isbf = flag[0];
  float el[ED_];
#pragma unroll
  for (int d = 0; d < ED_; ++d) el[d] = es[d];

  const int b = tid >> 4, q = tid & 15;
  float acc[4];
#pragma unroll
  for (int j = 0; j < 4; ++j) acc[j] = 0.f;

  for (int k0 = 0; k0 < KIP; k0 += 32) {
#pragma unroll
    for (int i = 0; i < O*8/256; ++i) {
      const int idx = tid + i*256;
      const int o = idx >> 3, kq = (idx & 7) * 4;
      const float4 a4 = merge_w<O, KIP>(WbF, WbH, el, o, k0 + kq, isbf);
      *(float4*)&wm[o][kq] = a4;
    }
    __syncthreads();
#pragma unroll
    for (int kq = 0; kq < 8; ++kq) {
      const float4 xv = *(const float4*)&xg[b][k0 + kq*4];
#pragma unroll
      for (int j = 0; j < 4; ++j) {
        const float4 wv = *(const float4*)&wm[q + 16*j][kq*4];
        acc[j] += xv.x*wv.x + xv.y*wv.y + xv.z*wv.z + xv.w*wv.w;
      }
    }
    __syncthreads();
  }
#pragma unroll
  for (int j = 0; j < 4; ++j) {
    const int o = q + 16*j;
    const float hc = tanhf(acc[j] + buv[n*64 + o]);
    const float rr = r_buf[(size_t)n*BH + b*64 + o];
    const float hold = hstate[(size_t)n*BH + b*64 + o];
    hstate[(size_t)n*BH + b*64 + o] = rr*hold + (1.f - rr)*hc;
  }
}

__global__ void k_zero_f(float* __restrict__ p, int n) {
  const int i = blockIdx.x*256 + threadIdx.x;
  if (i < n) p[i] = 0.f;
}
__global__ void k_zero_out(void* __restrict__ out, int nelem,
                           const int* __restrict__ flag) {
  const int i = blockIdx.x*256 + threadIdx.x;
  if (i < nelem) {
    if (flag[0]) ((unsigned short*)out)[i] = 0;
    else         ((float*)out)[i] = 0.f;
  }
}

// out[b][hor][n] = sum_c h2[n][b*64+c]*cwf[hor][c] + cbf[hor]
__global__ __launch_bounds__(256) void k_conv(const float* __restrict__ h2,
                                              const float* __restrict__ cwf,
                                              const float* __restrict__ cbf,
                                              void* __restrict__ out,
                                              const int* __restrict__ flag) {
  const int n = blockIdx.x, tid = threadIdx.x;
  __shared__ float hs[BH];
  for (int i = tid; i < BH; i += 256) hs[i] = h2[(size_t)n*BH + i];
  __syncthreads();
  const int isbf = flag[0];
  for (int i = tid; i < B_*HOR_; i += 256) {
    const int b = i / HOR_, hor = i - b*HOR_;
    float acc = cbf[hor];
#pragma unroll
    for (int c = 0; c < HID_; ++c) acc += hs[b*HID_ + c]*cwf[hor*HID_ + c];
    const size_t oi = (size_t)(b*HOR_ + hor)*N_ + n;
    if (isbf) ((bf16*)out)[oi] = f2b(acc);
    else      ((float*)out)[oi] = acc;
  }
}

// ---------------------------------------------------------------------------
extern "C" void kernel_launch(void* const* d_in, const int* in_sizes, int n_in,
                              void* d_out, int out_size, void* d_ws, size_t ws_size,
                              hipStream_t stream) {
  const void* src = d_in[0];
  const void* E   = d_in[1];
  const void* Wg0 = d_in[2];
  const void* bg0 = d_in[3];
  const void* Wu0 = d_in[4];
  const void* bu0 = d_in[5];
  const void* Wg1 = d_in[6];
  const void* bg1 = d_in[7];
  const void* Wu1 = d_in[8];
  const void* bu1 = d_in[9];
  const void* cw  = d_in[10];
  const void* cb  = d_in[11];
  (void)in_sizes; (void)n_in;

  char* p = (char*)d_ws;
  auto alloc = [&](size_t bytes) -> char* {
    char* r = p; p += (bytes + 255) & ~(size_t)255; return r;
  };
  const size_t SL = (size_t)N_*BH;
  int*   flag  = (int*)  alloc(256);
  float* Ein   = (float*)alloc((size_t)N_*ED_*4);
  float* cwf   = (float*)alloc((size_t)HOR_*HID_*4);
  float* cbf   = (float*)alloc((size_t)HOR_*4);
  float* S_f   = (float*)alloc((size_t)N_*N_*4);
  float* Wg0F  = (float*)alloc((size_t)ED_*128*160*4);
  float* Wu0F  = (float*)alloc((size_t)ED_*64*160*4);
  float* Wg1F  = (float*)alloc((size_t)ED_*128*256*4);
  float* Wu1F  = (float*)alloc((size_t)ED_*64*256*4);
  bf16*  Wg0H  = (bf16*) alloc((size_t)ED_*128*160*2);
  bf16*  Wu0H  = (bf16*) alloc((size_t)ED_*64*160*2);
  bf16*  Wg1H  = (bf16*) alloc((size_t)ED_*128*256*2);
  bf16*  Wu1H  = (bf16*) alloc((size_t)ED_*64*256*2);
  float* bgv0  = (float*)alloc((size_t)N_*128*4);
  float* buv0  = (float*)alloc((size_t)N_*64*4);
  float* bgv1  = (float*)alloc((size_t)N_*128*4);
  float* buv1  = (float*)alloc((size_t)N_*64*4);
  float* srcf  = (float*)alloc((size_t)BT*N_*4);
  float* Sx0   = (float*)alloc((size_t)N_*BT*4);
  float* h0    = (float*)alloc(SL*4);              // h0,h2 adjacent (one zero)
  float* h2    = (float*)alloc(SL*4);
  float* Sh_a  = (float*)alloc(SL*4);              // Sh_a,Sh_b adjacent
  float* Sh_b  = (float*)alloc(SL*4);              // Sh_b doubles as Szh buf
  float* zh    = (float*)alloc(SL*4);
  float* r_buf = (float*)alloc(SL*4);

  auto cdiv = [](int a, int b) { return (a + b - 1) / b; };

  k_detect<<<dim3(1), 256, 0, stream>>>(E, flag);

  const size_t required = (size_t)(p - (char*)d_ws);
  if (required > ws_size) {
    k_zero_out<<<dim3(cdiv(out_size, 256)), 256, 0, stream>>>(d_out, out_size, flag);
    return;
  }

  // --- casts + setup ---
  k_castE  <<<dim3(cdiv(N_*ED_, 256)), 256, 0, stream>>>(E, Ein, flag);
  k_castsrc<<<dim3(cdiv(BT*N_, 256)),  256, 0, stream>>>(src, srcf, flag);
  k_castc  <<<dim3(cdiv(HOR_*HID_, 256)), 256, 0, stream>>>(cw, cb, cwf, cbf, flag);
  k_prepT<0><<<dim3(cdiv(ED_*128*160, 256)), 256, 0, stream>>>(Wg0, Wg0F, Wg0H, 65, 160, 128, flag);
  k_prepT<0><<<dim3(cdiv(ED_*64*160,  256)), 256, 0, stream>>>(Wu0, Wu0F, Wu0H, 65, 160, 64, flag);
  k_prepT<1><<<dim3(cdiv(ED_*128*256, 256)), 256, 0, stream>>>(Wg1, Wg1F, Wg1H, 128, 256, 128, flag);
  k_prepT<1><<<dim3(cdiv(ED_*64*256,  256)), 256, 0, stream>>>(Wu1, Wu1F, Wu1H, 128, 256, 64, flag);
  k_matb<<<dim3(N_), 128, 0, stream>>>(Ein, bg0, bgv0, 128, flag);
  k_matb<<<dim3(N_), 128, 0, stream>>>(Ein, bu0, buv0, 64,  flag);
  k_matb<<<dim3(N_), 128, 0, stream>>>(Ein, bg1, bgv1, 128, flag);
  k_matb<<<dim3(N_), 128, 0, stream>>>(Ein, bu1, buv1, 64,  flag);
  k_softmax_S<<<dim3(N_), 256, 0, stream>>>(Ein, S_f);

  // Sx0[n, bt] = sum_m S[n,m]*srcf[bt*N + m]
  k_gemm64T<<<dim3(N_/64, BT/64), 256, 0, stream>>>(S_f, srcf, Sx0, N_, BT);

  // zero recurrent states + Sh_a/Sh_b (adjacent pairs; needed for t=0 reads)
  k_zero_f<<<dim3((int)((2*SL + 255)/256)), 256, 0, stream>>>(h0, (int)(2*SL));
  k_zero_f<<<dim3((int)((2*SL + 255)/256)), 256, 0, stream>>>(Sh_a, (int)(2*SL));

  // --- t = 0 (states zero: all Sh terms vanish except S@h1[0]) ---
  k_gateW<0,160><<<dim3(N_), 256, 0, stream>>>(Wg0F, Wg0H, bgv0, h0, srcf, Sh_a, Sx0,
                                               Ein, h0, zh, r_buf, flag, 0);
  k_candW<0,160><<<dim3(N_), 256, 0, stream>>>(Wu0F, Wu0H, buv0, zh, srcf, Sh_b, Sx0,
                                               Ein, r_buf, h0, flag, 0);
  // Sh_a = S@h1[0]  (direct store)
  k_gemm64D<<<dim3(N_/64, BH/64), 256, 0, stream>>>(S_f, h0, Sh_a, BH, BH,
                                                    h0, Sh_a, BH, BH, 1 << 30);
  k_gateW<1,256><<<dim3(N_), 256, 0, stream>>>(Wg1F, Wg1H, bgv1, h0, h2, Sh_a, Sh_b,
                                               Ein, h2, zh, r_buf, flag, 0);
  k_candW<1,256><<<dim3(N_), 256, 0, stream>>>(Wu1F, Wu1H, buv1, h0, zh, Sh_a, Sh_b,
                                               Ein, r_buf, h2, flag, 0);

  // --- t >= 1: Sh_a from previous step's dual GEMM serves L0's S@h ---
  for (int t = 1; t < T_; ++t) {
    k_gateW<0,160><<<dim3(N_), 256, 0, stream>>>(Wg0F, Wg0H, bgv0, h0, srcf, Sh_a, Sx0,
                                                 Ein, h0, zh, r_buf, flag, t);
    // Szh0 -> Sh_b (direct store)
    k_gemm64D<<<dim3(N_/64, BH/64), 256, 0, stream>>>(S_f, zh, Sh_b, BH, BH,
                                                      zh, Sh_b, BH, BH, 1 << 30);
    k_candW<0,160><<<dim3(N_), 256, 0, stream>>>(Wu0F, Wu0H, buv0, zh, srcf, Sh_b, Sx0,
                                                 Ein, r_buf, h0, flag, t);
    // h0 now holds h1[:, t]; dual: Sh_a = S@h1t, Sh_b = S@h2 (direct store)
    k_gemm64D<<<dim3(N_/64, 2*BH/64), 256, 0, stream>>>(S_f, h0, Sh_a, BH, BH,
                                                        h2, Sh_b, BH, BH, BH);
    k_gateW<1,256><<<dim3(N_), 256, 0, stream>>>(Wg1F, Wg1H, bgv1, h0, h2, Sh_a, Sh_b,
                                                 Ein, h2, zh, r_buf, flag, t);
    // Szh1 -> Sh_b (direct store)
    k_gemm64D<<<dim3(N_/64, BH/64), 256, 0, stream>>>(S_f, zh, Sh_b, BH, BH,
                                                      zh, Sh_b, BH, BH, 1 << 30);
    k_candW<1,256><<<dim3(N_), 256, 0, stream>>>(Wu1F, Wu1H, buv1, h0, zh, Sh_a, Sh_b,
                                                 Ein, r_buf, h2, flag, t);
  }

  // --- final conv ---
  k_conv<<<dim3(N_), 256, 0, stream>>>(h2, cwf, cbf, d_out, flag);
}

// Round 13
// 11913.492 us; speedup vs baseline: 1.2851x; 1.0500x over previous
//
#include <hip/hip_runtime.h>
#include <hip/hip_bf16.h>

// FP32-intermediate pipeline (recurrence is chaotic; bf16 rounding decorrelates).
// R13: packed d-interleaved basis weights. Gate/cand merge was latency-bound
//      (10 x 65KB-strided 8B loads per merged float4, VALUBusy 24%). Packed:
//      the 10 d-values for one (o,k4) are contiguous 80B -> 5 uint4 loads.
//      GEMM/schedule/mappings = R12 verbatim.

#define B_    16
#define T_    12
#define N_    2048
#define HID_  64
#define ED_   10
#define HOR_  12
#define BH    (B_*HID_)    // 1024
#define BT    (B_*T_)      // 192

typedef __hip_bfloat16 bf16;
__device__ __forceinline__ float b2f(bf16 x){ return __bfloat162float(x); }
__device__ __forceinline__ bf16  f2b(float x){ return __float2bfloat16(x); }
__device__ __forceinline__ float bits2f(unsigned u) {
  union { float f; unsigned i; } c; c.i = u << 16; return c.f;
}

__device__ __forceinline__ float ldin(const void* p, size_t i, int isbf) {
  return isbf ? b2f(((const bf16*)p)[i]) : ((const float*)p)[i];
}
__device__ __forceinline__ void fma4(float4& a, float s, const float4& b) {
  a.x += s*b.x; a.y += s*b.y; a.z += s*b.z; a.w += s*b.w;
}

// ---------------------------------------------------------------------------
// dtype detector on E (bits 14:7 of 32-bit words: bf16 exponent vs mantissa)
// ---------------------------------------------------------------------------
__global__ void k_detect(const void* __restrict__ E, int* __restrict__ flag) {
  __shared__ int cnt;
  if (threadIdx.x == 0) cnt = 0;
  __syncthreads();
  const unsigned* w = (const unsigned*)E;
  int c = 0;
  for (int i = threadIdx.x; i < 4096; i += 256) {
    const unsigned e = (w[i] >> 7) & 0xFFu;
    if (e >= 0x6Eu && e <= 0x86u) ++c;
  }
  atomicAdd(&cnt, c);
  __syncthreads();
  if (threadIdx.x == 0) flag[0] = (cnt > 2048) ? 1 : 0;
}

// --- input casts to fp32 internal buffers ---
__global__ void k_castE(const void* __restrict__ E, float* __restrict__ Ein,
                        const int* __restrict__ flag) {
  const int i = blockIdx.x*256 + threadIdx.x;
  if (i < N_*ED_) Ein[i] = ldin(E, i, flag[0]);
}
__global__ void k_castsrc(const void* __restrict__ src, float* __restrict__ srcf,
                          const int* __restrict__ flag) {
  const int i = blockIdx.x*256 + threadIdx.x;
  if (i < B_*T_*N_) srcf[i] = ldin(src, i, flag[0]);
}
__global__ void k_castc(const void* __restrict__ cw, const void* __restrict__ cb,
                        float* __restrict__ cwf, float* __restrict__ cbf,
                        const int* __restrict__ flag) {
  const int i = blockIdx.x*256 + threadIdx.x;
  const int f = flag[0];
  if (i < HOR_*HID_) cwf[i] = ldin(cw, i, f);
  if (i < HOR_)      cbf[i] = ldin(cb, i, f);
}

// ---------------------------------------------------------------------------
// S = softmax(relu(Ein @ Ein^T), axis=1) -> fp32 row-major
// ---------------------------------------------------------------------------
__global__ __launch_bounds__(256) void k_softmax_S(const float* __restrict__ Ein,
                                                   float* __restrict__ S) {
  const int n = blockIdx.x, tid = threadIdx.x;
  __shared__ float er[ED_];
  __shared__ float red[4];
  if (tid < ED_) er[tid] = Ein[n*ED_ + tid];
  __syncthreads();
  float e[ED_];
#pragma unroll
  for (int d = 0; d < ED_; ++d) e[d] = er[d];
  float v[8];
  float mx = 0.f;
#pragma unroll
  for (int j = 0; j < 8; ++j) {
    const int m = tid + j*256;
    float dot = 0.f;
#pragma unroll
    for (int d = 0; d < ED_; ++d) dot += e[d]*Ein[m*ED_ + d];
    v[j] = fmaxf(dot, 0.f);
    mx = fmaxf(mx, v[j]);
  }
  for (int o = 32; o; o >>= 1) mx = fmaxf(mx, __shfl_xor(mx, o, 64));
  if ((tid & 63) == 0) red[tid >> 6] = mx;
  __syncthreads();
  mx = fmaxf(fmaxf(red[0], red[1]), fmaxf(red[2], red[3]));
  __syncthreads();
  float sum = 0.f;
#pragma unroll
  for (int j = 0; j < 8; ++j) { v[j] = __expf(v[j] - mx); sum += v[j]; }
  for (int o = 32; o; o >>= 1) sum += __shfl_xor(sum, o, 64);
  if ((tid & 63) == 0) red[tid >> 6] = sum;
  __syncthreads();
  sum = red[0] + red[1] + red[2] + red[3];
  const float inv = 1.f / sum;
#pragma unroll
  for (int j = 0; j < 8; ++j)
    S[(size_t)n*N_ + tid + j*256] = v[j]*inv;
}

// ---------------------------------------------------------------------------
// Basis weights -> PACKED d-interleaved layout, fp32 + bf16:
//   P[((o*(KIP/4) + kg)*10 + d)*4 + e]  where kp = 4*kg + e.
// One (o,kg) group = 10 d x 4 elems contiguous (80 B bf16 / 160 B fp32).
// K-remap: LAYER0 (KIin=65,KIP=160): kp<64 ->(cheb0,kp+1); kp==64 ->(cheb0,0);
//   80<=kp<144 ->(cheb1,kp-79); kp==144 ->(cheb1,0); else 0.
// LAYER1 (KIin=128,KIP=256): cheb=kp>>7, i=kp&127.
// ---------------------------------------------------------------------------
template<int LAYER>
__global__ __launch_bounds__(256) void k_prepP(const void* __restrict__ Wb,
                                               float* __restrict__ PF,
                                               bf16* __restrict__ PH,
                                               int KIin, int KIP, int O,
                                               const int* __restrict__ flag) {
  const int idx = blockIdx.x*256 + threadIdx.x;
  if (idx >= ED_*O*KIP) return;
  const int d = idx / (O*KIP), rem = idx - d*O*KIP;
  const int o = rem / KIP, kp = rem - o*KIP;
  int cheb, i; bool valid;
  if (LAYER == 0) {
    cheb = (kp >= 80) ? 1 : 0;
    const int local = kp - cheb*80;
    if (local < 64)       { i = local + 1; valid = true; }
    else if (local == 64) { i = 0;         valid = true; }
    else                  { i = 0;         valid = false; }
  } else {
    cheb = kp >> 7; i = kp & 127; valid = true;
  }
  float v = 0.f;
  if (valid) v = ldin(Wb, (size_t)((d*2 + cheb)*KIin + i)*O + o, flag[0]);
  const int kg = kp >> 2, e = kp & 3;
  const size_t pi = ((size_t)(o*(KIP/4) + kg)*ED_ + d)*4 + e;
  PF[pi] = v;
  PH[pi] = f2b(v);   // exact in bf16-world
}

// bias vectors: outv[n][o] = sum_d Ein[n,d]*bb[d][o]
__global__ __launch_bounds__(128) void k_matb(const float* __restrict__ Ein,
                                              const void* __restrict__ bb,
                                              float* __restrict__ outv, int O,
                                              const int* __restrict__ flag) {
  const int n = blockIdx.x, tid = threadIdx.x;
  if (tid >= O) return;
  const int f = flag[0];
  float acc = 0.f;
#pragma unroll
  for (int d = 0; d < ED_; ++d) acc += Ein[n*ED_ + d]*ldin(bb, d*O + tid, f);
  outv[n*O + tid] = acc;
}

// ---------------------------------------------------------------------------
// Small 64-tile GEMM for Sx0 only (XT form: X[c*ldx+m]); cols = BT = 192
// ---------------------------------------------------------------------------
__global__ __launch_bounds__(256) void k_gemm64T(const float* __restrict__ S,
                                                 const float* __restrict__ X,
                                                 float* __restrict__ C,
                                                 int ldx, int ldc) {
  const int bm = blockIdx.x * 64;
  const int bc = blockIdx.y * 64;
  __shared__ float St[64][68];
  __shared__ float Xt[64][68];
  const int tid = threadIdx.x;
  const int r0 = (tid >> 4) * 4;
  const int c0 = (tid & 15) * 4;
  float acc[4][4];
#pragma unroll
  for (int i = 0; i < 4; ++i)
#pragma unroll
    for (int j = 0; j < 4; ++j) acc[i][j] = 0.f;
  for (int mk = 0; mk < N_; mk += 64) {
    {
      const int r = tid >> 2, ks = (tid & 3) * 16;
      const float* sp = S + (size_t)(bm + r)*N_ + mk + ks;
#pragma unroll
      for (int u = 0; u < 16; ++u) St[ks + u][r] = sp[u];
      const float* xp = X + (size_t)(bc + r)*ldx + mk + ks;
#pragma unroll
      for (int u = 0; u < 16; ++u) Xt[ks + u][r] = xp[u];
    }
    __syncthreads();
#pragma unroll 4
    for (int kk = 0; kk < 64; ++kk) {
      const float a0 = St[kk][r0], a1 = St[kk][r0+1],
                  a2 = St[kk][r0+2], a3 = St[kk][r0+3];
      const float b0 = Xt[kk][c0], b1 = Xt[kk][c0+1],
                  b2 = Xt[kk][c0+2], b3 = Xt[kk][c0+3];
      acc[0][0] += a0*b0; acc[0][1] += a0*b1; acc[0][2] += a0*b2; acc[0][3] += a0*b3;
      acc[1][0] += a1*b0; acc[1][1] += a1*b1; acc[1][2] += a1*b2; acc[1][3] += a1*b3;
      acc[2][0] += a2*b0; acc[2][1] += a2*b1; acc[2][2] += a2*b2; acc[2][3] += a2*b3;
      acc[3][0] += a3*b0; acc[3][1] += a3*b1; acc[3][2] += a3*b2; acc[3][3] += a3*b3;
    }
    __syncthreads();
  }
#pragma unroll
  for (int i = 0; i < 4; ++i)
#pragma unroll
    for (int j = 0; j < 4; ++j)
      C[(size_t)(bm + r0 + i)*ldc + bc + c0 + j] = acc[i][j];
}

// ---------------------------------------------------------------------------
// Main 64x64-tile fp32 GEMM (R8 lineage — measured at its 57% FMA-issue
// ceiling): C(n,c) = sum_m S[n,m] * X[m*ldx + c]. TK=32, 4x4 micro, direct
// store. Grid: (N/64, cols/64). Dual: blockIdx.y*64 >= split -> X2/C2.
// ---------------------------------------------------------------------------
__global__ __launch_bounds__(256) void k_gemm64D(const float* __restrict__ S,
                                                 const float* __restrict__ X1,
                                                 float* __restrict__ C1,
                                                 int ldx1, int ldc1,
                                                 const float* __restrict__ X2,
                                                 float* __restrict__ C2,
                                                 int ldx2, int ldc2,
                                                 int split) {
  const int bm = blockIdx.x * 64;
  int bc = blockIdx.y * 64;
  const float* X = X1; float* C = C1; int ldx = ldx1, ldc = ldc1;
  if (bc >= split) { X = X2; C = C2; ldx = ldx2; ldc = ldc2; bc -= split; }

  __shared__ float Ss[32][68];   // Ss[kk][r] = S[bm+r][mk+kk]
  __shared__ float Xs[32][68];   // Xs[kk][c] = X[mk+kk][bc+c]
  const int tid = threadIdx.x;
  const int r0 = (tid >> 4) * 4;
  const int c0 = (tid & 15) * 4;

  float acc[4][4];
#pragma unroll
  for (int i = 0; i < 4; ++i)
#pragma unroll
    for (int j = 0; j < 4; ++j) acc[i][j] = 0.f;

  for (int mk = 0; mk < N_; mk += 32) {
    // stage S: 64 rows x 32 k = 512 float4 (transposed scatter)
#pragma unroll
    for (int u = 0; u < 2; ++u) {
      const int idx = tid + u*256;
      const int r = idx >> 3, kq = (idx & 7) * 4;
      const float4 v4 = *(const float4*)(S + (size_t)(bm + r)*N_ + mk + kq);
      Ss[kq + 0][r] = v4.x; Ss[kq + 1][r] = v4.y;
      Ss[kq + 2][r] = v4.z; Ss[kq + 3][r] = v4.w;
    }
    // stage X: 32 k x 64 c = 512 float4 (natural)
#pragma unroll
    for (int u = 0; u < 2; ++u) {
      const int idx = tid + u*256;
      const int kk = idx >> 4, cq = (idx & 15) * 4;
      *(float4*)&Xs[kk][cq] = *(const float4*)(X + (size_t)(mk + kk)*ldx + bc + cq);
    }
    __syncthreads();
#pragma unroll 8
    for (int kk = 0; kk < 32; ++kk) {
      const float4 a4 = *(const float4*)&Ss[kk][r0];
      const float4 b4 = *(const float4*)&Xs[kk][c0];
      const float a[4] = {a4.x, a4.y, a4.z, a4.w};
      const float b[4] = {b4.x, b4.y, b4.z, b4.w};
#pragma unroll
      for (int i = 0; i < 4; ++i)
#pragma unroll
        for (int j = 0; j < 4; ++j) acc[i][j] += a[i]*b[j];
    }
    __syncthreads();
  }
#pragma unroll
  for (int i = 0; i < 4; ++i) {
    float4 o4;
    o4.x = acc[i][0]; o4.y = acc[i][1]; o4.z = acc[i][2]; o4.w = acc[i][3];
    *(float4*)(C + (size_t)(bm + r0 + i)*ldc + bc + c0) = o4;
  }
}

// ---------------------------------------------------------------------------
// xg builder (float4): xg[b][k], padded row stride KIPP.
// LAYER0 (KIP=160): k<64:h(p0); k==64:x(p1,(b*T+t)*N+n); [80,144):Sh(p2);
//   k==144:Sx(p3,n*BT+b*T+t); else 0.
// LAYER1 (KIP=256): [0,64)p0 |[64,128)p1 |[128,192)p2 |[192,256)p3, n-major.
// ---------------------------------------------------------------------------
template<int LAYER, int KIP, int KIPP>
__device__ __forceinline__ void build4(float (*xg)[KIPP],
                                       const float* p0, const float* p1,
                                       const float* p2, const float* p3,
                                       int n, int t, int tid) {
  constexpr int NQ = KIP/4;
  for (int idx = tid; idx < B_*NQ; idx += 256) {
    const int b = idx / NQ, k = (idx - b*NQ) * 4;
    float4 v = make_float4(0.f, 0.f, 0.f, 0.f);
    if (LAYER == 1) {
      const float* rg = (k < 64) ? p0 : (k < 128) ? p1 : (k < 192) ? p2 : p3;
      v = *(const float4*)(rg + (size_t)n*BH + b*64 + (k & 63));
    } else {
      if (k < 64)        v = *(const float4*)(p0 + (size_t)n*BH + b*64 + k);
      else if (k == 64)  v.x = p1[(size_t)(b*T_ + t)*N_ + n];
      else if (k >= 80 && k < 144)
                         v = *(const float4*)(p2 + (size_t)n*BH + b*64 + (k - 80));
      else if (k == 144) v.x = p3[(size_t)n*BT + b*T_ + t];
    }
    *(float4*)&xg[b][k] = v;
  }
}

// ---------------------------------------------------------------------------
// Packed merge: a4[e] = sum_d el[d] * P[(o,kg) group][d][e].
// bf16: 5 contiguous uint4 (80 B); fp32: 10 contiguous float4 (160 B).
// ---------------------------------------------------------------------------
template<int KIP>
__device__ __forceinline__ float4 merge_p(const float* __restrict__ PF,
                                          const bf16* __restrict__ PH,
                                          const float* el, int o, int kg,
                                          int isbf) {
  float4 a4 = make_float4(0.f, 0.f, 0.f, 0.f);
  const size_t gbase = (size_t)(o*(KIP/4) + kg)*(ED_*4);
  if (isbf) {
    const uint4* g = (const uint4*)(PH + gbase);
#pragma unroll
    for (int i = 0; i < 5; ++i) {
      const uint4 w = g[i];                       // d=2i (x,y), d=2i+1 (z,w)
      const float e0 = el[2*i], e1 = el[2*i + 1];
      a4.x += e0*bits2f(w.x & 0xFFFFu); a4.y += e0*bits2f(w.x >> 16);
      a4.z += e0*bits2f(w.y & 0xFFFFu); a4.w += e0*bits2f(w.y >> 16);
      a4.x += e1*bits2f(w.z & 0xFFFFu); a4.y += e1*bits2f(w.z >> 16);
      a4.z += e1*bits2f(w.w & 0xFFFFu); a4.w += e1*bits2f(w.w >> 16);
    }
  } else {
    const float4* g = (const float4*)(PF + gbase);
#pragma unroll
    for (int d = 0; d < ED_; ++d)
      fma4(a4, el[d], g[d]);
  }
  return a4;
}

// ---------------------------------------------------------------------------
// Gate: y[b,o] = sigmoid(sum_d E[n,d]*(xg[b,:]@Wb[d][:,o]) + bgv[n,o]), O=128.
// ---------------------------------------------------------------------------
template<int LAYER, int KIP>
__global__ __launch_bounds__(256) void k_gateW(const float* __restrict__ PF,
                                               const bf16* __restrict__ PH,
                                               const float* __restrict__ bgv,
                                               const float* __restrict__ p0,
                                               const float* __restrict__ p1,
                                               const float* __restrict__ p2,
                                               const float* __restrict__ p3,
                                               const float* __restrict__ Ein,
                                               const float* __restrict__ hstate,
                                               float* __restrict__ zh,
                                               float* __restrict__ r_buf,
                                               const int* __restrict__ flag,
                                               int t) {
  constexpr int KIPP = KIP + 4;
  constexpr int O = 128;
  const int n = blockIdx.x, tid = threadIdx.x;
  __shared__ float xg[B_][KIPP];
  __shared__ float wm[O][36];
  __shared__ float es[ED_];
  if (tid < ED_) es[tid] = Ein[n*ED_ + tid];
  build4<LAYER, KIP, KIPP>(xg, p0, p1, p2, p3, n, t, tid);
  __syncthreads();
  const int isbf = flag[0];
  float el[ED_];
#pragma unroll
  for (int d = 0; d < ED_; ++d) el[d] = es[d];

  const int b = tid >> 4, q = tid & 15;
  float acc[8];
#pragma unroll
  for (int j = 0; j < 8; ++j) acc[j] = 0.f;

  for (int k0 = 0; k0 < KIP; k0 += 32) {
#pragma unroll
    for (int i = 0; i < O*8/256; ++i) {
      const int idx = tid + i*256;
      const int o = idx >> 3, kq = idx & 7;
      const float4 a4 = merge_p<KIP>(PF, PH, el, o, (k0 >> 2) + kq, isbf);
      *(float4*)&wm[o][kq*4] = a4;
    }
    __syncthreads();
#pragma unroll
    for (int kq = 0; kq < 8; ++kq) {
      const float4 xv = *(const float4*)&xg[b][k0 + kq*4];
#pragma unroll
      for (int j = 0; j < 8; ++j) {
        const float4 wv = *(const float4*)&wm[q + 16*j][kq*4];
        acc[j] += xv.x*wv.x + xv.y*wv.y + xv.z*wv.z + xv.w*wv.w;
      }
    }
    __syncthreads();
  }
#pragma unroll
  for (int j = 0; j < 8; ++j) {
    const int o = q + 16*j;
    float s = acc[j] + bgv[n*128 + o];
    s = 1.f/(1.f + __expf(-s));
    if (o < HID_)
      zh[(size_t)n*BH + b*64 + o] = s*hstate[(size_t)n*BH + b*64 + o];
    else
      r_buf[(size_t)n*BH + b*64 + (o - HID_)] = s;
  }
}

// ---------------------------------------------------------------------------
// Candidate: hc = tanh(...); h = r*h + (1-r)*hc in place. O=64.
// ---------------------------------------------------------------------------
template<int LAYER, int KIP>
__global__ __launch_bounds__(256) void k_candW(const float* __restrict__ PF,
                                               const bf16* __restrict__ PH,
                                               const float* __restrict__ buv,
                                               const float* __restrict__ p0,
                                               const float* __restrict__ p1,
                                               const float* __restrict__ p2,
                                               const float* __restrict__ p3,
                                               const float* __restrict__ Ein,
                                               const float* __restrict__ r_buf,
                                               float* __restrict__ hstate,
                                               const int* __restrict__ flag,
                                               int t) {
  constexpr int KIPP = KIP + 4;
  constexpr int O = 64;
  const int n = blockIdx.x, tid = threadIdx.x;
  __shared__ float xg[B_][KIPP];
  __shared__ float wm[O][36];
  __shared__ float es[ED_];
  if (tid < ED_) es[tid] = Ein[n*ED_ + tid];
  build4<LAYER, KIP, KIPP>(xg, p0, p1, p2, p3, n, t, tid);
  __syncthreads();
  const int isbf = flag[0];
  float el[ED_];
#pragma unroll
  for (int d = 0; d < ED_; ++d) el[d] = es[d];

  const int b = tid >> 4, q = tid & 15;
  float acc[4];
#pragma unroll
  for (int j = 0; j < 4; ++j) acc[j] = 0.f;

  for (int k0 = 0; k0 < KIP; k0 += 32) {
#pragma unroll
    for (int i = 0; i < O*8/256; ++i) {
      const int idx = tid + i*256;
      const int o = idx >> 3, kq = idx & 7;
      const float4 a4 = merge_p<KIP>(PF, PH, el, o, (k0 >> 2) + kq, isbf);
      *(float4*)&wm[o][kq*4] = a4;
    }
    __syncthreads();
#pragma unroll
    for (int kq = 0; kq < 8; ++kq) {
      const float4 xv = *(const float4*)&xg[b][k0 + kq*4];
#pragma unroll
      for (int j = 0; j < 4; ++j) {
        const float4 wv = *(const float4*)&wm[q + 16*j][kq*4];
        acc[j] += xv.x*wv.x + xv.y*wv.y + xv.z*wv.z + xv.w*wv.w;
      }
    }
    __syncthreads();
  }
#pragma unroll
  for (int j = 0; j < 4; ++j) {
    const int o = q + 16*j;
    const float hc = tanhf(acc[j] + buv[n*64 + o]);
    const float rr = r_buf[(size_t)n*BH + b*64 + o];
    const float hold = hstate[(size_t)n*BH + b*64 + o];
    hstate[(size_t)n*BH + b*64 + o] = rr*hold + (1.f - rr)*hc;
  }
}

__global__ void k_zero_f(float* __restrict__ p, int n) {
  const int i = blockIdx.x*256 + threadIdx.x;
  if (i < n) p[i] = 0.f;
}
__global__ void k_zero_out(void* __restrict__ out, int nelem,
                           const int* __restrict__ flag) {
  const int i = blockIdx.x*256 + threadIdx.x;
  if (i < nelem) {
    if (flag[0]) ((unsigned short*)out)[i] = 0;
    else         ((float*)out)[i] = 0.f;
  }
}

// out[b][hor][n] = sum_c h2[n][b*64+c]*cwf[hor][c] + cbf[hor]
__global__ __launch_bounds__(256) void k_conv(const float* __restrict__ h2,
                                              const float* __restrict__ cwf,
                                              const float* __restrict__ cbf,
                                              void* __restrict__ out,
                                              const int* __restrict__ flag) {
  const int n = blockIdx.x, tid = threadIdx.x;
  __shared__ float hs[BH];
  for (int i = tid; i < BH; i += 256) hs[i] = h2[(size_t)n*BH + i];
  __syncthreads();
  const int isbf = flag[0];
  for (int i = tid; i < B_*HOR_; i += 256) {
    const int b = i / HOR_, hor = i - b*HOR_;
    float acc = cbf[hor];
#pragma unroll
    for (int c = 0; c < HID_; ++c) acc += hs[b*HID_ + c]*cwf[hor*HID_ + c];
    const size_t oi = (size_t)(b*HOR_ + hor)*N_ + n;
    if (isbf) ((bf16*)out)[oi] = f2b(acc);
    else      ((float*)out)[oi] = acc;
  }
}

// ---------------------------------------------------------------------------
extern "C" void kernel_launch(void* const* d_in, const int* in_sizes, int n_in,
                              void* d_out, int out_size, void* d_ws, size_t ws_size,
                              hipStream_t stream) {
  const void* src = d_in[0];
  const void* E   = d_in[1];
  const void* Wg0 = d_in[2];
  const void* bg0 = d_in[3];
  const void* Wu0 = d_in[4];
  const void* bu0 = d_in[5];
  const void* Wg1 = d_in[6];
  const void* bg1 = d_in[7];
  const void* Wu1 = d_in[8];
  const void* bu1 = d_in[9];
  const void* cw  = d_in[10];
  const void* cb  = d_in[11];
  (void)in_sizes; (void)n_in;

  char* p = (char*)d_ws;
  auto alloc = [&](size_t bytes) -> char* {
    char* r = p; p += (bytes + 255) & ~(size_t)255; return r;
  };
  const size_t SL = (size_t)N_*BH;
  int*   flag  = (int*)  alloc(256);
  float* Ein   = (float*)alloc((size_t)N_*ED_*4);
  float* cwf   = (float*)alloc((size_t)HOR_*HID_*4);
  float* cbf   = (float*)alloc((size_t)HOR_*4);
  float* S_f   = (float*)alloc((size_t)N_*N_*4);
  float* Wg0F  = (float*)alloc((size_t)ED_*128*160*4);
  float* Wu0F  = (float*)alloc((size_t)ED_*64*160*4);
  float* Wg1F  = (float*)alloc((size_t)ED_*128*256*4);
  float* Wu1F  = (float*)alloc((size_t)ED_*64*256*4);
  bf16*  Wg0H  = (bf16*) alloc((size_t)ED_*128*160*2);
  bf16*  Wu0H  = (bf16*) alloc((size_t)ED_*64*160*2);
  bf16*  Wg1H  = (bf16*) alloc((size_t)ED_*128*256*2);
  bf16*  Wu1H  = (bf16*) alloc((size_t)ED_*64*256*2);
  float* bgv0  = (float*)alloc((size_t)N_*128*4);
  float* buv0  = (float*)alloc((size_t)N_*64*4);
  float* bgv1  = (float*)alloc((size_t)N_*128*4);
  float* buv1  = (float*)alloc((size_t)N_*64*4);
  float* srcf  = (float*)alloc((size_t)BT*N_*4);
  float* Sx0   = (float*)alloc((size_t)N_*BT*4);
  float* h0    = (float*)alloc(SL*4);              // h0,h2 adjacent (one zero)
  float* h2    = (float*)alloc(SL*4);
  float* Sh_a  = (float*)alloc(SL*4);              // Sh_a,Sh_b adjacent
  float* Sh_b  = (float*)alloc(SL*4);              // Sh_b doubles as Szh buf
  float* zh    = (float*)alloc(SL*4);
  float* r_buf = (float*)alloc(SL*4);

  auto cdiv = [](int a, int b) { return (a + b - 1) / b; };

  k_detect<<<dim3(1), 256, 0, stream>>>(E, flag);

  const size_t required = (size_t)(p - (char*)d_ws);
  if (required > ws_size) {
    k_zero_out<<<dim3(cdiv(out_size, 256)), 256, 0, stream>>>(d_out, out_size, flag);
    return;
  }

  // --- casts + setup ---
  k_castE  <<<dim3(cdiv(N_*ED_, 256)), 256, 0, stream>>>(E, Ein, flag);
  k_castsrc<<<dim3(cdiv(BT*N_, 256)),  256, 0, stream>>>(src, srcf, flag);
  k_castc  <<<dim3(cdiv(HOR_*HID_, 256)), 256, 0, stream>>>(cw, cb, cwf, cbf, flag);
  k_prepP<0><<<dim3(cdiv(ED_*128*160, 256)), 256, 0, stream>>>(Wg0, Wg0F, Wg0H, 65, 160, 128, flag);
  k_prepP<0><<<dim3(cdiv(ED_*64*160,  256)), 256, 0, stream>>>(Wu0, Wu0F, Wu0H, 65, 160, 64, flag);
  k_prepP<1><<<dim3(cdiv(ED_*128*256, 256)), 256, 0, stream>>>(Wg1, Wg1F, Wg1H, 128, 256, 128, flag);
  k_prepP<1><<<dim3(cdiv(ED_*64*256,  256)), 256, 0, stream>>>(Wu1, Wu1F, Wu1H, 128, 256, 64, flag);
  k_matb<<<dim3(N_), 128, 0, stream>>>(Ein, bg0, bgv0, 128, flag);
  k_matb<<<dim3(N_), 128, 0, stream>>>(Ein, bu0, buv0, 64,  flag);
  k_matb<<<dim3(N_), 128, 0, stream>>>(Ein, bg1, bgv1, 128, flag);
  k_matb<<<dim3(N_), 128, 0, stream>>>(Ein, bu1, buv1, 64,  flag);
  k_softmax_S<<<dim3(N_), 256, 0, stream>>>(Ein, S_f);

  // Sx0[n, bt] = sum_m S[n,m]*srcf[bt*N + m]
  k_gemm64T<<<dim3(N_/64, BT/64), 256, 0, stream>>>(S_f, srcf, Sx0, N_, BT);

  // zero recurrent states + Sh_a/Sh_b (adjacent pairs; needed for t=0 reads)
  k_zero_f<<<dim3((int)((2*SL + 255)/256)), 256, 0, stream>>>(h0, (int)(2*SL));
  k_zero_f<<<dim3((int)((2*SL + 255)/256)), 256, 0, stream>>>(Sh_a, (int)(2*SL));

  // --- t = 0 (states zero: all Sh terms vanish except S@h1[0]) ---
  k_gateW<0,160><<<dim3(N_), 256, 0, stream>>>(Wg0F, Wg0H, bgv0, h0, srcf, Sh_a, Sx0,
                                               Ein, h0, zh, r_buf, flag, 0);
  k_candW<0,160><<<dim3(N_), 256, 0, stream>>>(Wu0F, Wu0H, buv0, zh, srcf, Sh_b, Sx0,
                                               Ein, r_buf, h0, flag, 0);
  // Sh_a = S@h1[0]  (direct store)
  k_gemm64D<<<dim3(N_/64, BH/64), 256, 0, stream>>>(S_f, h0, Sh_a, BH, BH,
                                                    h0, Sh_a, BH, BH, 1 << 30);
  k_gateW<1,256><<<dim3(N_), 256, 0, stream>>>(Wg1F, Wg1H, bgv1, h0, h2, Sh_a, Sh_b,
                                               Ein, h2, zh, r_buf, flag, 0);
  k_candW<1,256><<<dim3(N_), 256, 0, stream>>>(Wu1F, Wu1H, buv1, h0, zh, Sh_a, Sh_b,
                                               Ein, r_buf, h2, flag, 0);

  // --- t >= 1: Sh_a from previous step's dual GEMM serves L0's S@h ---
  for (int t = 1; t < T_; ++t) {
    k_gateW<0,160><<<dim3(N_), 256, 0, stream>>>(Wg0F, Wg0H, bgv0, h0, srcf, Sh_a, Sx0,
                                                 Ein, h0, zh, r_buf, flag, t);
    // Szh0 -> Sh_b (direct store)
    k_gemm64D<<<dim3(N_/64, BH/64), 256, 0, stream>>>(S_f, zh, Sh_b, BH, BH,
                                                      zh, Sh_b, BH, BH, 1 << 30);
    k_candW<0,160><<<dim3(N_), 256, 0, stream>>>(Wu0F, Wu0H, buv0, zh, srcf, Sh_b, Sx0,
                                                 Ein, r_buf, h0, flag, t);
    // h0 now holds h1[:, t]; dual: Sh_a = S@h1t, Sh_b = S@h2 (direct store)
    k_gemm64D<<<dim3(N_/64, 2*BH/64), 256, 0, stream>>>(S_f, h0, Sh_a, BH, BH,
                                                        h2, Sh_b, BH, BH, BH);
    k_gateW<1,256><<<dim3(N_), 256, 0, stream>>>(Wg1F, Wg1H, bgv1, h0, h2, Sh_a, Sh_b,
                                                 Ein, h2, zh, r_buf, flag, t);
    // Szh1 -> Sh_b (direct store)
    k_gemm64D<<<dim3(N_/64, BH/64), 256, 0, stream>>>(S_f, zh, Sh_b, BH, BH,
                                                      zh, Sh_b, BH, BH, 1 << 30);
    k_candW<1,256><<<dim3(N_), 256, 0, stream>>>(Wu1F, Wu1H, buv1, h0, zh, Sh_a, Sh_b,
                                                 Ein, r_buf, h2, flag, t);
  }

  // --- final conv ---
  k_conv<<<dim3(N_), 256, 0, stream>>>(h2, cwf, cbf, d_out, flag);
}

// Round 14
// 9425.130 us; speedup vs baseline: 1.6243x; 1.2640x over previous
//
#include <hip/hip_runtime.h>
#include <hip/hip_bf16.h>

// FP32-intermediate pipeline; R14: split-bf16 MFMA GEMM.
// S@X ~= Sh@Xh + Sl@Xh + Sh@Xl (hi/lo bf16 pairs, fp32 accumulate): rel err
// ~2^-17 (safe vs chaos gain; bf16-direct's 4e-3 was not). Producers write
// transposed hi/lo copies; S split once. 3 MFMA per staged tile pair.

#define B_    16
#define T_    12
#define N_    2048
#define HID_  64
#define ED_   10
#define HOR_  12
#define BH    (B_*HID_)    // 1024
#define BT    (B_*T_)      // 192

typedef __hip_bfloat16 bf16;
typedef __attribute__((ext_vector_type(8))) short short8;
typedef __attribute__((ext_vector_type(4))) float floatx4;

__device__ __forceinline__ float b2f(bf16 x){ return __bfloat162float(x); }
__device__ __forceinline__ bf16  f2b(float x){ return __float2bfloat16(x); }
__device__ __forceinline__ float bits2f(unsigned u) {
  union { float f; unsigned i; } c; c.i = u << 16; return c.f;
}
__device__ __forceinline__ float ldin(const void* p, size_t i, int isbf) {
  return isbf ? b2f(((const bf16*)p)[i]) : ((const float*)p)[i];
}
__device__ __forceinline__ void fma4(float4& a, float s, const float4& b) {
  a.x += s*b.x; a.y += s*b.y; a.z += s*b.z; a.w += s*b.w;
}

// ---------------------------------------------------------------------------
// dtype detector on E (bits 14:7 of 32-bit words: bf16 exponent vs mantissa)
// ---------------------------------------------------------------------------
__global__ void k_detect(const void* __restrict__ E, int* __restrict__ flag) {
  __shared__ int cnt;
  if (threadIdx.x == 0) cnt = 0;
  __syncthreads();
  const unsigned* w = (const unsigned*)E;
  int c = 0;
  for (int i = threadIdx.x; i < 4096; i += 256) {
    const unsigned e = (w[i] >> 7) & 0xFFu;
    if (e >= 0x6Eu && e <= 0x86u) ++c;
  }
  atomicAdd(&cnt, c);
  __syncthreads();
  if (threadIdx.x == 0) flag[0] = (cnt > 2048) ? 1 : 0;
}

// --- input casts to fp32 internal buffers ---
__global__ void k_castE(const void* __restrict__ E, float* __restrict__ Ein,
                        const int* __restrict__ flag) {
  const int i = blockIdx.x*256 + threadIdx.x;
  if (i < N_*ED_) Ein[i] = ldin(E, i, flag[0]);
}
__global__ void k_castsrc(const void* __restrict__ src, float* __restrict__ srcf,
                          const int* __restrict__ flag) {
  const int i = blockIdx.x*256 + threadIdx.x;
  if (i < B_*T_*N_) srcf[i] = ldin(src, i, flag[0]);
}
__global__ void k_castc(const void* __restrict__ cw, const void* __restrict__ cb,
                        float* __restrict__ cwf, float* __restrict__ cbf,
                        const int* __restrict__ flag) {
  const int i = blockIdx.x*256 + threadIdx.x;
  const int f = flag[0];
  if (i < HOR_*HID_) cwf[i] = ldin(cw, i, f);
  if (i < HOR_)      cbf[i] = ldin(cb, i, f);
}

// ---------------------------------------------------------------------------
// S = softmax(relu(Ein @ Ein^T), axis=1) -> fp32 row-major
// ---------------------------------------------------------------------------
__global__ __launch_bounds__(256) void k_softmax_S(const float* __restrict__ Ein,
                                                   float* __restrict__ S) {
  const int n = blockIdx.x, tid = threadIdx.x;
  __shared__ float er[ED_];
  __shared__ float red[4];
  if (tid < ED_) er[tid] = Ein[n*ED_ + tid];
  __syncthreads();
  float e[ED_];
#pragma unroll
  for (int d = 0; d < ED_; ++d) e[d] = er[d];
  float v[8];
  float mx = 0.f;
#pragma unroll
  for (int j = 0; j < 8; ++j) {
    const int m = tid + j*256;
    float dot = 0.f;
#pragma unroll
    for (int d = 0; d < ED_; ++d) dot += e[d]*Ein[m*ED_ + d];
    v[j] = fmaxf(dot, 0.f);
    mx = fmaxf(mx, v[j]);
  }
  for (int o = 32; o; o >>= 1) mx = fmaxf(mx, __shfl_xor(mx, o, 64));
  if ((tid & 63) == 0) red[tid >> 6] = mx;
  __syncthreads();
  mx = fmaxf(fmaxf(red[0], red[1]), fmaxf(red[2], red[3]));
  __syncthreads();
  float sum = 0.f;
#pragma unroll
  for (int j = 0; j < 8; ++j) { v[j] = __expf(v[j] - mx); sum += v[j]; }
  for (int o = 32; o; o >>= 1) sum += __shfl_xor(sum, o, 64);
  if ((tid & 63) == 0) red[tid >> 6] = sum;
  __syncthreads();
  sum = red[0] + red[1] + red[2] + red[3];
  const float inv = 1.f / sum;
#pragma unroll
  for (int j = 0; j < 8; ++j)
    S[(size_t)n*N_ + tid + j*256] = v[j]*inv;
}

// split fp32 -> hi/lo bf16 pair
__global__ void k_splitS(const float* __restrict__ S, bf16* __restrict__ Sh,
                         bf16* __restrict__ Sl, int n) {
  const int i = blockIdx.x*256 + threadIdx.x;
  if (i < n) {
    const float v = S[i];
    const bf16 h = f2b(v);
    Sh[i] = h;
    Sl[i] = f2b(v - b2f(h));
  }
}

// ---------------------------------------------------------------------------
// Basis weights -> PACKED d-interleaved layout, fp32 + bf16 (R13 verbatim).
// ---------------------------------------------------------------------------
template<int LAYER>
__global__ __launch_bounds__(256) void k_prepP(const void* __restrict__ Wb,
                                               float* __restrict__ PF,
                                               bf16* __restrict__ PH,
                                               int KIin, int KIP, int O,
                                               const int* __restrict__ flag) {
  const int idx = blockIdx.x*256 + threadIdx.x;
  if (idx >= ED_*O*KIP) return;
  const int d = idx / (O*KIP), rem = idx - d*O*KIP;
  const int o = rem / KIP, kp = rem - o*KIP;
  int cheb, i; bool valid;
  if (LAYER == 0) {
    cheb = (kp >= 80) ? 1 : 0;
    const int local = kp - cheb*80;
    if (local < 64)       { i = local + 1; valid = true; }
    else if (local == 64) { i = 0;         valid = true; }
    else                  { i = 0;         valid = false; }
  } else {
    cheb = kp >> 7; i = kp & 127; valid = true;
  }
  float v = 0.f;
  if (valid) v = ldin(Wb, (size_t)((d*2 + cheb)*KIin + i)*O + o, flag[0]);
  const int kg = kp >> 2, e = kp & 3;
  const size_t pi = ((size_t)(o*(KIP/4) + kg)*ED_ + d)*4 + e;
  PF[pi] = v;
  PH[pi] = f2b(v);
}

// bias vectors: outv[n][o] = sum_d Ein[n,d]*bb[d][o]
__global__ __launch_bounds__(128) void k_matb(const float* __restrict__ Ein,
                                              const void* __restrict__ bb,
                                              float* __restrict__ outv, int O,
                                              const int* __restrict__ flag) {
  const int n = blockIdx.x, tid = threadIdx.x;
  if (tid >= O) return;
  const int f = flag[0];
  float acc = 0.f;
#pragma unroll
  for (int d = 0; d < ED_; ++d) acc += Ein[n*ED_ + d]*ldin(bb, d*O + tid, f);
  outv[n*O + tid] = acc;
}

// ---------------------------------------------------------------------------
// Small 64-tile fp32 GEMM for Sx0 only (setup; XT form X[c*ldx+m]); cols=192
// ---------------------------------------------------------------------------
__global__ __launch_bounds__(256) void k_gemm64T(const float* __restrict__ S,
                                                 const float* __restrict__ X,
                                                 float* __restrict__ C,
                                                 int ldx, int ldc) {
  const int bm = blockIdx.x * 64;
  const int bc = blockIdx.y * 64;
  __shared__ float St[64][68];
  __shared__ float Xt[64][68];
  const int tid = threadIdx.x;
  const int r0 = (tid >> 4) * 4;
  const int c0 = (tid & 15) * 4;
  float acc[4][4];
#pragma unroll
  for (int i = 0; i < 4; ++i)
#pragma unroll
    for (int j = 0; j < 4; ++j) acc[i][j] = 0.f;
  for (int mk = 0; mk < N_; mk += 64) {
    {
      const int r = tid >> 2, ks = (tid & 3) * 16;
      const float* sp = S + (size_t)(bm + r)*N_ + mk + ks;
#pragma unroll
      for (int u = 0; u < 16; ++u) St[ks + u][r] = sp[u];
      const float* xp = X + (size_t)(bc + r)*ldx + mk + ks;
#pragma unroll
      for (int u = 0; u < 16; ++u) Xt[ks + u][r] = xp[u];
    }
    __syncthreads();
#pragma unroll 4
    for (int kk = 0; kk < 64; ++kk) {
      const float a0 = St[kk][r0], a1 = St[kk][r0+1],
                  a2 = St[kk][r0+2], a3 = St[kk][r0+3];
      const float b0 = Xt[kk][c0], b1 = Xt[kk][c0+1],
                  b2 = Xt[kk][c0+2], b3 = Xt[kk][c0+3];
      acc[0][0] += a0*b0; acc[0][1] += a0*b1; acc[0][2] += a0*b2; acc[0][3] += a0*b3;
      acc[1][0] += a1*b0; acc[1][1] += a1*b1; acc[1][2] += a1*b2; acc[1][3] += a1*b3;
      acc[2][0] += a2*b0; acc[2][1] += a2*b1; acc[2][2] += a2*b2; acc[2][3] += a2*b3;
      acc[3][0] += a3*b0; acc[3][1] += a3*b1; acc[3][2] += a3*b2; acc[3][3] += a3*b3;
    }
    __syncthreads();
  }
#pragma unroll
  for (int i = 0; i < 4; ++i)
#pragma unroll
    for (int j = 0; j < 4; ++j)
      C[(size_t)(bm + r0 + i)*ldc + bc + c0 + j] = acc[i][j];
}

// ---------------------------------------------------------------------------
// Split-bf16 MFMA GEMM: C(n,c) = sum_m S[n,m]*X[m,c], S = Sh+Sl, X = Xh+Xl
// (transposed bc-major bf16 pairs, row stride N_). 3 MFMA per staged tile:
// Sh@Xh + Sl@Xh + Sh@Xl. 64x64 tile, BK=32, fp32 out, direct store.
// Dual: blockIdx.y*64 >= split -> X2/C2 (col rebased).
// Verified layouts: A m=lane&15,k=quad*8+j [m120]; C/D col=lane&15,
// row=quad*4+reg [m89].
// ---------------------------------------------------------------------------
__global__ __launch_bounds__(256) void k_gemmM(const bf16* __restrict__ Sh,
                                               const bf16* __restrict__ Sl,
                                               const bf16* __restrict__ X1h,
                                               const bf16* __restrict__ X1l,
                                               float* __restrict__ C1, int ldc1,
                                               const bf16* __restrict__ X2h,
                                               const bf16* __restrict__ X2l,
                                               float* __restrict__ C2, int ldc2,
                                               int split) {
  const int bm = blockIdx.x * 64;
  int bc = blockIdx.y * 64;
  const bf16* Xh = X1h; const bf16* Xl = X1l; float* C = C1; int ldc = ldc1;
  if (bc >= split) { Xh = X2h; Xl = X2l; C = C2; ldc = ldc2; bc -= split; }

  __shared__ __align__(16) bf16 Ah[64][40];
  __shared__ __align__(16) bf16 Al[64][40];
  __shared__ __align__(16) bf16 Bh[64][40];
  __shared__ __align__(16) bf16 Bl[64][40];
  const int tid = threadIdx.x;
  const int wave = tid >> 6, lane = tid & 63, q = lane >> 4, ln = lane & 15;
  const int rs = tid >> 2, ks = (tid & 3) * 8;

  floatx4 acc[4];
#pragma unroll
  for (int ct = 0; ct < 4; ++ct) acc[ct] = (floatx4){0.f,0.f,0.f,0.f};

  for (int mk = 0; mk < N_; mk += 32) {
    *(uint4*)&Ah[rs][ks] = *(const uint4*)(Sh + (size_t)(bm + rs)*N_ + mk + ks);
    *(uint4*)&Al[rs][ks] = *(const uint4*)(Sl + (size_t)(bm + rs)*N_ + mk + ks);
    *(uint4*)&Bh[rs][ks] = *(const uint4*)(Xh + (size_t)(bc + rs)*N_ + mk + ks);
    *(uint4*)&Bl[rs][ks] = *(const uint4*)(Xl + (size_t)(bc + rs)*N_ + mk + ks);
    __syncthreads();
    const short8 ah = *(const short8*)&Ah[wave*16 + ln][q*8];
    const short8 al = *(const short8*)&Al[wave*16 + ln][q*8];
#pragma unroll
    for (int ct = 0; ct < 4; ++ct) {
      const short8 bh = *(const short8*)&Bh[ct*16 + ln][q*8];
      const short8 bl = *(const short8*)&Bl[ct*16 + ln][q*8];
      acc[ct] = __builtin_amdgcn_mfma_f32_16x16x32_bf16(ah, bh, acc[ct], 0, 0, 0);
      acc[ct] = __builtin_amdgcn_mfma_f32_16x16x32_bf16(al, bh, acc[ct], 0, 0, 0);
      acc[ct] = __builtin_amdgcn_mfma_f32_16x16x32_bf16(ah, bl, acc[ct], 0, 0, 0);
    }
    __syncthreads();
  }
#pragma unroll
  for (int ct = 0; ct < 4; ++ct)
#pragma unroll
    for (int r = 0; r < 4; ++r)
      C[(size_t)(bm + wave*16 + q*4 + r)*ldc + bc + ct*16 + ln] = acc[ct][r];
}

// ---------------------------------------------------------------------------
// xg builder (float4): xg[b][k], padded row stride KIPP (R13 verbatim).
// ---------------------------------------------------------------------------
template<int LAYER, int KIP, int KIPP>
__device__ __forceinline__ void build4(float (*xg)[KIPP],
                                       const float* p0, const float* p1,
                                       const float* p2, const float* p3,
                                       int n, int t, int tid) {
  constexpr int NQ = KIP/4;
  for (int idx = tid; idx < B_*NQ; idx += 256) {
    const int b = idx / NQ, k = (idx - b*NQ) * 4;
    float4 v = make_float4(0.f, 0.f, 0.f, 0.f);
    if (LAYER == 1) {
      const float* rg = (k < 64) ? p0 : (k < 128) ? p1 : (k < 192) ? p2 : p3;
      v = *(const float4*)(rg + (size_t)n*BH + b*64 + (k & 63));
    } else {
      if (k < 64)        v = *(const float4*)(p0 + (size_t)n*BH + b*64 + k);
      else if (k == 64)  v.x = p1[(size_t)(b*T_ + t)*N_ + n];
      else if (k >= 80 && k < 144)
                         v = *(const float4*)(p2 + (size_t)n*BH + b*64 + (k - 80));
      else if (k == 144) v.x = p3[(size_t)n*BT + b*T_ + t];
    }
    *(float4*)&xg[b][k] = v;
  }
}

// Packed merge (R13 verbatim)
template<int KIP>
__device__ __forceinline__ float4 merge_p(const float* __restrict__ PF,
                                          const bf16* __restrict__ PH,
                                          const float* el, int o, int kg,
                                          int isbf) {
  float4 a4 = make_float4(0.f, 0.f, 0.f, 0.f);
  const size_t gbase = (size_t)(o*(KIP/4) + kg)*(ED_*4);
  if (isbf) {
    const uint4* g = (const uint4*)(PH + gbase);
#pragma unroll
    for (int i = 0; i < 5; ++i) {
      const uint4 w = g[i];
      const float e0 = el[2*i], e1 = el[2*i + 1];
      a4.x += e0*bits2f(w.x & 0xFFFFu); a4.y += e0*bits2f(w.x >> 16);
      a4.z += e0*bits2f(w.y & 0xFFFFu); a4.w += e0*bits2f(w.y >> 16);
      a4.x += e1*bits2f(w.z & 0xFFFFu); a4.y += e1*bits2f(w.z >> 16);
      a4.z += e1*bits2f(w.w & 0xFFFFu); a4.w += e1*bits2f(w.w >> 16);
    }
  } else {
    const float4* g = (const float4*)(PF + gbase);
#pragma unroll
    for (int d = 0; d < ED_; ++d)
      fma4(a4, el[d], g[d]);
  }
  return a4;
}

// ---------------------------------------------------------------------------
// Gate: zh fp32 n-major + transposed hi/lo bf16 copies (for MFMA GEMM).
// ---------------------------------------------------------------------------
template<int LAYER, int KIP>
__global__ __launch_bounds__(256) void k_gateW(const float* __restrict__ PF,
                                               const bf16* __restrict__ PH,
                                               const float* __restrict__ bgv,
                                               const float* __restrict__ p0,
                                               const float* __restrict__ p1,
                                               const float* __restrict__ p2,
                                               const float* __restrict__ p3,
                                               const float* __restrict__ Ein,
                                               const float* __restrict__ hstate,
                                               float* __restrict__ zh,
                                               bf16* __restrict__ zhTh,
                                               bf16* __restrict__ zhTl,
                                               float* __restrict__ r_buf,
                                               const int* __restrict__ flag,
                                               int t) {
  constexpr int KIPP = KIP + 4;
  constexpr int O = 128;
  const int n = blockIdx.x, tid = threadIdx.x;
  __shared__ float xg[B_][KIPP];
  __shared__ float wm[O][36];
  __shared__ float es[ED_];
  if (tid < ED_) es[tid] = Ein[n*ED_ + tid];
  build4<LAYER, KIP, KIPP>(xg, p0, p1, p2, p3, n, t, tid);
  __syncthreads();
  const int isbf = flag[0];
  float el[ED_];
#pragma unroll
  for (int d = 0; d < ED_; ++d) el[d] = es[d];

  const int b = tid >> 4, q = tid & 15;
  float acc[8];
#pragma unroll
  for (int j = 0; j < 8; ++j) acc[j] = 0.f;

  for (int k0 = 0; k0 < KIP; k0 += 32) {
#pragma unroll
    for (int i = 0; i < O*8/256; ++i) {
      const int idx = tid + i*256;
      const int o = idx >> 3, kq = idx & 7;
      const float4 a4 = merge_p<KIP>(PF, PH, el, o, (k0 >> 2) + kq, isbf);
      *(float4*)&wm[o][kq*4] = a4;
    }
    __syncthreads();
#pragma unroll
    for (int kq = 0; kq < 8; ++kq) {
      const float4 xv = *(const float4*)&xg[b][k0 + kq*4];
#pragma unroll
      for (int j = 0; j < 8; ++j) {
        const float4 wv = *(const float4*)&wm[q + 16*j][kq*4];
        acc[j] += xv.x*wv.x + xv.y*wv.y + xv.z*wv.z + xv.w*wv.w;
      }
    }
    __syncthreads();
  }
#pragma unroll
  for (int j = 0; j < 8; ++j) {
    const int o = q + 16*j;
    float s = acc[j] + bgv[n*128 + o];
    s = 1.f/(1.f + __expf(-s));
    if (o < HID_) {
      const float zv = s*hstate[(size_t)n*BH + b*64 + o];
      zh[(size_t)n*BH + b*64 + o] = zv;
      const bf16 h = f2b(zv);
      zhTh[(size_t)(b*64 + o)*N_ + n] = h;
      zhTl[(size_t)(b*64 + o)*N_ + n] = f2b(zv - b2f(h));
    } else {
      r_buf[(size_t)n*BH + b*64 + (o - HID_)] = s;
    }
  }
}

// ---------------------------------------------------------------------------
// Candidate: h fp32 n-major (in place) + transposed hi/lo bf16 copies.
// ---------------------------------------------------------------------------
template<int LAYER, int KIP>
__global__ __launch_bounds__(256) void k_candW(const float* __restrict__ PF,
                                               const bf16* __restrict__ PH,
                                               const float* __restrict__ buv,
                                               const float* __restrict__ p0,
                                               const float* __restrict__ p1,
                                               const float* __restrict__ p2,
                                               const float* __restrict__ p3,
                                               const float* __restrict__ Ein,
                                               const float* __restrict__ r_buf,
                                               float* __restrict__ hstate,
                                               bf16* __restrict__ hTh,
                                               bf16* __restrict__ hTl,
                                               const int* __restrict__ flag,
                                               int t) {
  constexpr int KIPP = KIP + 4;
  constexpr int O = 64;
  const int n = blockIdx.x, tid = threadIdx.x;
  __shared__ float xg[B_][KIPP];
  __shared__ float wm[O][36];
  __shared__ float es[ED_];
  if (tid < ED_) es[tid] = Ein[n*ED_ + tid];
  build4<LAYER, KIP, KIPP>(xg, p0, p1, p2, p3, n, t, tid);
  __syncthreads();
  const int isbf = flag[0];
  float el[ED_];
#pragma unroll
  for (int d = 0; d < ED_; ++d) el[d] = es[d];

  const int b = tid >> 4, q = tid & 15;
  float acc[4];
#pragma unroll
  for (int j = 0; j < 4; ++j) acc[j] = 0.f;

  for (int k0 = 0; k0 < KIP; k0 += 32) {
#pragma unroll
    for (int i = 0; i < O*8/256; ++i) {
      const int idx = tid + i*256;
      const int o = idx >> 3, kq = idx & 7;
      const float4 a4 = merge_p<KIP>(PF, PH, el, o, (k0 >> 2) + kq, isbf);
      *(float4*)&wm[o][kq*4] = a4;
    }
    __syncthreads();
#pragma unroll
    for (int kq = 0; kq < 8; ++kq) {
      const float4 xv = *(const float4*)&xg[b][k0 + kq*4];
#pragma unroll
      for (int j = 0; j < 4; ++j) {
        const float4 wv = *(const float4*)&wm[q + 16*j][kq*4];
        acc[j] += xv.x*wv.x + xv.y*wv.y + xv.z*wv.z + xv.w*wv.w;
      }
    }
    __syncthreads();
  }
#pragma unroll
  for (int j = 0; j < 4; ++j) {
    const int o = q + 16*j;
    const float hc = tanhf(acc[j] + buv[n*64 + o]);
    const float rr = r_buf[(size_t)n*BH + b*64 + o];
    const float hold = hstate[(size_t)n*BH + b*64 + o];
    const float hn = rr*hold + (1.f - rr)*hc;
    hstate[(size_t)n*BH + b*64 + o] = hn;
    const bf16 h = f2b(hn);
    hTh[(size_t)(b*64 + o)*N_ + n] = h;
    hTl[(size_t)(b*64 + o)*N_ + n] = f2b(hn - b2f(h));
  }
}

__global__ void k_zero_f(float* __restrict__ p, int n) {
  const int i = blockIdx.x*256 + threadIdx.x;
  if (i < n) p[i] = 0.f;
}
__global__ void k_zero_out(void* __restrict__ out, int nelem,
                           const int* __restrict__ flag) {
  const int i = blockIdx.x*256 + threadIdx.x;
  if (i < nelem) {
    if (flag[0]) ((unsigned short*)out)[i] = 0;
    else         ((float*)out)[i] = 0.f;
  }
}

// out[b][hor][n] = sum_c h2[n][b*64+c]*cwf[hor][c] + cbf[hor]
__global__ __launch_bounds__(256) void k_conv(const float* __restrict__ h2,
                                              const float* __restrict__ cwf,
                                              const float* __restrict__ cbf,
                                              void* __restrict__ out,
                                              const int* __restrict__ flag) {
  const int n = blockIdx.x, tid = threadIdx.x;
  __shared__ float hs[BH];
  for (int i = tid; i < BH; i += 256) hs[i] = h2[(size_t)n*BH + i];
  __syncthreads();
  const int isbf = flag[0];
  for (int i = tid; i < B_*HOR_; i += 256) {
    const int b = i / HOR_, hor = i - b*HOR_;
    float acc = cbf[hor];
#pragma unroll
    for (int c = 0; c < HID_; ++c) acc += hs[b*HID_ + c]*cwf[hor*HID_ + c];
    const size_t oi = (size_t)(b*HOR_ + hor)*N_ + n;
    if (isbf) ((bf16*)out)[oi] = f2b(acc);
    else      ((float*)out)[oi] = acc;
  }
}

// ---------------------------------------------------------------------------
extern "C" void kernel_launch(void* const* d_in, const int* in_sizes, int n_in,
                              void* d_out, int out_size, void* d_ws, size_t ws_size,
                              hipStream_t stream) {
  const void* src = d_in[0];
  const void* E   = d_in[1];
  const void* Wg0 = d_in[2];
  const void* bg0 = d_in[3];
  const void* Wu0 = d_in[4];
  const void* bu0 = d_in[5];
  const void* Wg1 = d_in[6];
  const void* bg1 = d_in[7];
  const void* Wu1 = d_in[8];
  const void* bu1 = d_in[9];
  const void* cw  = d_in[10];
  const void* cb  = d_in[11];
  (void)in_sizes; (void)n_in;

  char* p = (char*)d_ws;
  auto alloc = [&](size_t bytes) -> char* {
    char* r = p; p += (bytes + 255) & ~(size_t)255; return r;
  };
  const size_t SL = (size_t)N_*BH;
  int*   flag  = (int*)  alloc(256);
  float* Ein   = (float*)alloc((size_t)N_*ED_*4);
  float* cwf   = (float*)alloc((size_t)HOR_*HID_*4);
  float* cbf   = (float*)alloc((size_t)HOR_*4);
  float* S_f   = (float*)alloc((size_t)N_*N_*4);
  bf16*  S_hi  = (bf16*) alloc((size_t)N_*N_*2);
  bf16*  S_lo  = (bf16*) alloc((size_t)N_*N_*2);
  float* Wg0F  = (float*)alloc((size_t)ED_*128*160*4);
  float* Wu0F  = (float*)alloc((size_t)ED_*64*160*4);
  float* Wg1F  = (float*)alloc((size_t)ED_*128*256*4);
  float* Wu1F  = (float*)alloc((size_t)ED_*64*256*4);
  bf16*  Wg0H  = (bf16*) alloc((size_t)ED_*128*160*2);
  bf16*  Wu0H  = (bf16*) alloc((size_t)ED_*64*160*2);
  bf16*  Wg1H  = (bf16*) alloc((size_t)ED_*128*256*2);
  bf16*  Wu1H  = (bf16*) alloc((size_t)ED_*64*256*2);
  float* bgv0  = (float*)alloc((size_t)N_*128*4);
  float* buv0  = (float*)alloc((size_t)N_*64*4);
  float* bgv1  = (float*)alloc((size_t)N_*128*4);
  float* buv1  = (float*)alloc((size_t)N_*64*4);
  float* srcf  = (float*)alloc((size_t)BT*N_*4);
  float* Sx0   = (float*)alloc((size_t)N_*BT*4);
  float* h0    = (float*)alloc(SL*4);              // h0,h2 adjacent (one zero)
  float* h2    = (float*)alloc(SL*4);
  float* Sh_a  = (float*)alloc(SL*4);              // Sh_a,Sh_b adjacent
  float* Sh_b  = (float*)alloc(SL*4);
  float* zh    = (float*)alloc(SL*4);
  float* r_buf = (float*)alloc(SL*4);
  bf16*  zhTh  = (bf16*) alloc(SL*2);
  bf16*  zhTl  = (bf16*) alloc(SL*2);
  bf16*  h0Th  = (bf16*) alloc(SL*2);
  bf16*  h0Tl  = (bf16*) alloc(SL*2);
  bf16*  h2Th  = (bf16*) alloc(SL*2);
  bf16*  h2Tl  = (bf16*) alloc(SL*2);

  auto cdiv = [](int a, int b) { return (a + b - 1) / b; };

  k_detect<<<dim3(1), 256, 0, stream>>>(E, flag);

  const size_t required = (size_t)(p - (char*)d_ws);
  if (required > ws_size) {
    k_zero_out<<<dim3(cdiv(out_size, 256)), 256, 0, stream>>>(d_out, out_size, flag);
    return;
  }

  // --- casts + setup ---
  k_castE  <<<dim3(cdiv(N_*ED_, 256)), 256, 0, stream>>>(E, Ein, flag);
  k_castsrc<<<dim3(cdiv(BT*N_, 256)),  256, 0, stream>>>(src, srcf, flag);
  k_castc  <<<dim3(cdiv(HOR_*HID_, 256)), 256, 0, stream>>>(cw, cb, cwf, cbf, flag);
  k_prepP<0><<<dim3(cdiv(ED_*128*160, 256)), 256, 0, stream>>>(Wg0, Wg0F, Wg0H, 65, 160, 128, flag);
  k_prepP<0><<<dim3(cdiv(ED_*64*160,  256)), 256, 0, stream>>>(Wu0, Wu0F, Wu0H, 65, 160, 64, flag);
  k_prepP<1><<<dim3(cdiv(ED_*128*256, 256)), 256, 0, stream>>>(Wg1, Wg1F, Wg1H, 128, 256, 128, flag);
  k_prepP<1><<<dim3(cdiv(ED_*64*256,  256)), 256, 0, stream>>>(Wu1, Wu1F, Wu1H, 128, 256, 64, flag);
  k_matb<<<dim3(N_), 128, 0, stream>>>(Ein, bg0, bgv0, 128, flag);
  k_matb<<<dim3(N_), 128, 0, stream>>>(Ein, bu0, buv0, 64,  flag);
  k_matb<<<dim3(N_), 128, 0, stream>>>(Ein, bg1, bgv1, 128, flag);
  k_matb<<<dim3(N_), 128, 0, stream>>>(Ein, bu1, buv1, 64,  flag);
  k_softmax_S<<<dim3(N_), 256, 0, stream>>>(Ein, S_f);
  k_splitS<<<dim3(cdiv(N_*N_, 256)), 256, 0, stream>>>(S_f, S_hi, S_lo, N_*N_);

  // Sx0[n, bt] = sum_m S[n,m]*srcf[bt*N + m]  (setup, fp32 kernel)
  k_gemm64T<<<dim3(N_/64, BT/64), 256, 0, stream>>>(S_f, srcf, Sx0, N_, BT);

  // zero recurrent states + Sh_a/Sh_b (adjacent pairs; t=0 reads them)
  k_zero_f<<<dim3((int)((2*SL + 255)/256)), 256, 0, stream>>>(h0, (int)(2*SL));
  k_zero_f<<<dim3((int)((2*SL + 255)/256)), 256, 0, stream>>>(Sh_a, (int)(2*SL));

  // --- t = 0 (states zero: all Sh terms vanish except S@h1[0]) ---
  k_gateW<0,160><<<dim3(N_), 256, 0, stream>>>(Wg0F, Wg0H, bgv0, h0, srcf, Sh_a, Sx0,
                                               Ein, h0, zh, zhTh, zhTl, r_buf, flag, 0);
  k_candW<0,160><<<dim3(N_), 256, 0, stream>>>(Wu0F, Wu0H, buv0, zh, srcf, Sh_b, Sx0,
                                               Ein, r_buf, h0, h0Th, h0Tl, flag, 0);
  // Sh_a = S@h1[0]
  k_gemmM<<<dim3(N_/64, BH/64), 256, 0, stream>>>(S_hi, S_lo, h0Th, h0Tl, Sh_a, BH,
                                                  h0Th, h0Tl, Sh_a, BH, 1 << 30);
  k_gateW<1,256><<<dim3(N_), 256, 0, stream>>>(Wg1F, Wg1H, bgv1, h0, h2, Sh_a, Sh_b,
                                               Ein, h2, zh, zhTh, zhTl, r_buf, flag, 0);
  k_candW<1,256><<<dim3(N_), 256, 0, stream>>>(Wu1F, Wu1H, buv1, h0, zh, Sh_a, Sh_b,
                                               Ein, r_buf, h2, h2Th, h2Tl, flag, 0);

  // --- t >= 1: Sh_a from previous step's dual GEMM serves L0's S@h ---
  for (int t = 1; t < T_; ++t) {
    k_gateW<0,160><<<dim3(N_), 256, 0, stream>>>(Wg0F, Wg0H, bgv0, h0, srcf, Sh_a, Sx0,
                                                 Ein, h0, zh, zhTh, zhTl, r_buf, flag, t);
    // Szh0 -> Sh_b
    k_gemmM<<<dim3(N_/64, BH/64), 256, 0, stream>>>(S_hi, S_lo, zhTh, zhTl, Sh_b, BH,
                                                    zhTh, zhTl, Sh_b, BH, 1 << 30);
    k_candW<0,160><<<dim3(N_), 256, 0, stream>>>(Wu0F, Wu0H, buv0, zh, srcf, Sh_b, Sx0,
                                                 Ein, r_buf, h0, h0Th, h0Tl, flag, t);
    // h0 now holds h1[:, t]; dual: Sh_a = S@h1t, Sh_b = S@h2
    k_gemmM<<<dim3(N_/64, 2*BH/64), 256, 0, stream>>>(S_hi, S_lo, h0Th, h0Tl, Sh_a, BH,
                                                      h2Th, h2Tl, Sh_b, BH, BH);
    k_gateW<1,256><<<dim3(N_), 256, 0, stream>>>(Wg1F, Wg1H, bgv1, h0, h2, Sh_a, Sh_b,
                                                 Ein, h2, zh, zhTh, zhTl, r_buf, flag, t);
    // Szh1 -> Sh_b
    k_gemmM<<<dim3(N_/64, BH/64), 256, 0, stream>>>(S_hi, S_lo, zhTh, zhTl, Sh_b, BH,
                                                    zhTh, zhTl, Sh_b, BH, 1 << 30);
    k_candW<1,256><<<dim3(N_), 256, 0, stream>>>(Wu1F, Wu1H, buv1, h0, zh, Sh_a, Sh_b,
                                                 Ein, r_buf, h2, h2Th, h2Tl, flag, t);
  }

  // --- final conv ---
  k_conv<<<dim3(N_), 256, 0, stream>>>(h2, cwf, cbf, d_out, flag);
}